// Round 1
// baseline (1225.041 us; speedup 1.0000x reference)
//
#include <hip/hip_runtime.h>

typedef unsigned short ushort_t;
typedef unsigned int uint_t;

#define SCALE 0.17677669529663687f

__device__ __forceinline__ float blo(uint_t u) { return __uint_as_float(u << 16); }
__device__ __forceinline__ float bhi(uint_t u) { return __uint_as_float(u & 0xffff0000u); }
__device__ __forceinline__ float u2f(ushort_t u) { return __uint_as_float(((uint_t)u) << 16); }
// fp32 -> bf16 (RNE), finite inputs
__device__ __forceinline__ ushort_t f2u(float f) {
    const uint_t x = __float_as_uint(f);
    return (ushort_t)((x + 0x7fffu + ((x >> 16) & 1u)) >> 16);
}
__device__ __forceinline__ uint_t pack2(float a, float b) {
    return (uint_t)f2u(a) | ((uint_t)f2u(b) << 16);
}

// ==================================================================
// MAIN PATH: qkv materialized in ws as bf16 [p][j], p=131072, j=384.
// Requires ws_size >= 96 MB.
// ==================================================================

// ------------------------------------------------------------------
// k_qqkv: qkv[p, j] = bf16( sum_c x[b,c,p] * qkv_w[c,j] + qkv_b[j] )
// 64 pixels x 64 j per block; K=128 fully staged in LDS (fp32).
// ------------------------------------------------------------------
__global__ __launch_bounds__(256) void k_qqkv(
    const float* __restrict__ x, const float* __restrict__ w,
    const float* __restrict__ wb, ushort_t* __restrict__ qkv)
{
    __shared__ float a_lds[128 * 64];   // [c][p]
    __shared__ float b_lds[128 * 64];   // [c][j]
    const int t = threadIdx.x;
    const int tileP = blockIdx.x & 2047;       // 2048 pixel tiles of 64
    const int j0 = (blockIdx.x >> 11) * 64;    // 6 j tiles
    const int p0 = tileP * 64;
    const int b = p0 >> 14;                    // HW = 16384
    const int rem = p0 & 16383;
    const float* xb = x + ((size_t)b << 21) + rem;

    for (int i = t; i < 8192; i += 256) {
        const int c = i >> 6, p = i & 63;
        a_lds[i] = xb[c * 16384 + p];
    }
    for (int i = t; i < 8192; i += 256) {
        const int c = i >> 6, jj = i & 63;
        b_lds[i] = w[c * 384 + j0 + jj];
    }
    __syncthreads();

    const int tp = t >> 4, tj = t & 15;
    float acc[4][4];
#pragma unroll
    for (int i = 0; i < 4; ++i)
#pragma unroll
        for (int j = 0; j < 4; ++j) acc[i][j] = 0.f;

#pragma unroll 4
    for (int k = 0; k < 128; ++k) {
        const float4 av = *(const float4*)&a_lds[k * 64 + tp * 4];
        const float4 bv = *(const float4*)&b_lds[k * 64 + tj * 4];
        acc[0][0] += av.x * bv.x; acc[0][1] += av.x * bv.y; acc[0][2] += av.x * bv.z; acc[0][3] += av.x * bv.w;
        acc[1][0] += av.y * bv.x; acc[1][1] += av.y * bv.y; acc[1][2] += av.y * bv.z; acc[1][3] += av.y * bv.w;
        acc[2][0] += av.z * bv.x; acc[2][1] += av.z * bv.y; acc[2][2] += av.z * bv.z; acc[2][3] += av.z * bv.w;
        acc[3][0] += av.w * bv.x; acc[3][1] += av.w * bv.y; acc[3][2] += av.w * bv.z; acc[3][3] += av.w * bv.w;
    }

    float bb[4];
#pragma unroll
    for (int jj = 0; jj < 4; ++jj) bb[jj] = wb[j0 + tj * 4 + jj];
#pragma unroll
    for (int i = 0; i < 4; ++i) {
        uint2 o;
        o.x = pack2(acc[i][0] + bb[0], acc[i][1] + bb[1]);
        o.y = pack2(acc[i][2] + bb[2], acc[i][3] + bb[3]);
        *(uint2*)&qkv[(size_t)(p0 + tp * 4 + i) * 384 + j0 + tj * 4] = o;
    }
}

// ------------------------------------------------------------------
// k_attn2: per 8x8 window. k/v staged from qkv into LDS (bf16,
// stride-132), q from qkv into regs; attention; proj; OVERWRITE
// out = rate1 * xa (fp32).  Thread (h = t>>6, n = t&63).
// ------------------------------------------------------------------
__global__ __launch_bounds__(256) void k_attn2(
    const ushort_t* __restrict__ qkv, const float* __restrict__ pw,
    const float* __restrict__ pb, const float* __restrict__ rpb,
    const float* __restrict__ r1, float* __restrict__ out)
{
    __shared__ float arena[8450];   // kv (bf16) then xa (fp32), overlapped
    ushort_t* kvb = (ushort_t*)arena;
    uint_t* kv32 = (uint_t*)arena;
    const int t = threadIdx.x;
    const int b = blockIdx.x >> 8, wy = (blockIdx.x >> 4) & 15, wx = blockIdx.x & 15;
    const int prow0 = (b << 14) + (wy * 8) * 128 + wx * 8;
    const uint_t* qkvu = (const uint_t*)qkv;

    // stage k (j 128..255) and v (j 256..383): per m, 64 uints each
    for (int i = t; i < 4096; i += 256) {
        const int m = i >> 6, u = i & 63;
        const size_t pr = (size_t)(prow0 + (m >> 3) * 128 + (m & 7)) * 192;
        kv32[m * 66 + u]        = qkvu[pr + 64 + u];
        kv32[4224 + m * 66 + u] = qkvu[pr + 128 + u];
    }

    const int h = t >> 6, n = t & 63;
    const size_t pq = (size_t)(prow0 + (n >> 3) * 128 + (n & 7)) * 192;
    float qa[32];
    const uint_t* qrow = qkvu + pq + h * 16;
#pragma unroll
    for (int j = 0; j < 16; ++j) {
        const uint_t u = qrow[j];
        qa[2 * j]     = blo(u) * SCALE;
        qa[2 * j + 1] = bhi(u) * SCALE;
    }
    __syncthreads();

    const int ry = n >> 3, rx = n & 7;
    float sar[64];
    float mx = -1e30f;
#pragma unroll
    for (int m = 0; m < 64; ++m) {
        const uint2* kr = (const uint2*)(kvb + m * 132 + h * 32);
        float s = 0.f;
#pragma unroll
        for (int j = 0; j < 8; ++j) {
            const uint2 u = kr[j];
            s += qa[4 * j + 0] * blo(u.x) + qa[4 * j + 1] * bhi(u.x)
               + qa[4 * j + 2] * blo(u.y) + qa[4 * j + 3] * bhi(u.y);
        }
        s += rpb[((ry - (m >> 3) + 7) * 15 + (rx - (m & 7) + 7)) * 4 + h];
        sar[m] = s;
        mx = fmaxf(mx, s);
    }
    float l = 0.f;
#pragma unroll
    for (int m = 0; m < 64; ++m) { const float e = __expf(sar[m] - mx); sar[m] = e; l += e; }
    const float inv = 1.f / l;

    float acc[32];
#pragma unroll
    for (int cc = 0; cc < 32; ++cc) acc[cc] = 0.f;
#pragma unroll
    for (int m = 0; m < 64; ++m) {
        const float pm = sar[m];
        const uint2* vr = (const uint2*)(kvb + 8448 + m * 132 + h * 32);
#pragma unroll
        for (int j = 0; j < 8; ++j) {
            const uint2 u = vr[j];
            acc[4 * j + 0] += pm * blo(u.x); acc[4 * j + 1] += pm * bhi(u.x);
            acc[4 * j + 2] += pm * blo(u.y); acc[4 * j + 3] += pm * bhi(u.y);
        }
    }
    __syncthreads();   // all k/v reads done
#pragma unroll
    for (int cc = 0; cc < 32; ++cc) arena[n * 130 + h * 32 + cc] = acc[cc] * inv;
    __syncthreads();

    // proj: out = rate1 * (xa @ proj_w + proj_b)
    const int p = t & 63, jb = t >> 6;
    float aj[32];
#pragma unroll
    for (int jj = 0; jj < 32; ++jj) aj[jj] = pb[jb * 32 + jj];
    const float* xr = arena + p * 130;
    const float* pwb = pw + jb * 32;
    for (int c = 0; c < 128; ++c) {
        const float xv = xr[c];
        const float4* pr = (const float4*)(pwb + c * 128);
#pragma unroll
        for (int j = 0; j < 8; ++j) {
            const float4 w4 = pr[j];
            aj[4 * j + 0] += xv * w4.x; aj[4 * j + 1] += xv * w4.y;
            aj[4 * j + 2] += xv * w4.z; aj[4 * j + 3] += xv * w4.w;
        }
    }
    const float rate1 = r1[0];
    const int oy = wy * 8 + (p >> 3), ox = wx * 8 + (p & 7);
    float* ob = out + ((size_t)b << 21) + (size_t)(oy * 128 + ox);
#pragma unroll
    for (int jj = 0; jj < 32; ++jj)
        ob[(size_t)(jb * 32 + jj) << 14] = rate1 * aj[jj];
}

// ------------------------------------------------------------------
// k_conv2: per 16x16 tile, 8 chunks of 4 d.  f_c[i,d] at each 18x18
// halo pixel from materialized qkv (12 MACs per output), zero outside
// the image; then the 81-tap grouped conv; RMW out += rate2*(conv+db).
// ------------------------------------------------------------------
__global__ __launch_bounds__(256) void k_conv2(
    const ushort_t* __restrict__ qkv, const float* __restrict__ fcw,
    const float* __restrict__ fcb, const float* __restrict__ depw,
    const float* __restrict__ depb, const float* __restrict__ r2,
    float* __restrict__ out)
{
    __shared__ float fcl[11664];    // [(ii*4+dd)*324 + pix]
    __shared__ __align__(16) float dwl[1296];   // [kk81][16 oc-in-chunk]
    __shared__ float fcwl[108];
    __shared__ float fcbl[9];

    const int t = threadIdx.x;
    const int b = blockIdx.x >> 6, tile = blockIdx.x & 63;
    const int ty0 = (tile >> 3) << 4, tx0 = (tile & 7) << 4;
    if (t < 108) fcwl[t] = fcw[t];
    if (t < 9)   fcbl[t] = fcb[t];
    const float rate2 = r2[0];
    const int py = t >> 4, px = t & 15;
    float* ob = out + ((size_t)b << 21) + (size_t)((ty0 + py) * 128 + (tx0 + px));

    // this thread's halo pixels: pix0 = t, pix1 = 256+t (t<68)
    const int row0 = t / 18, col0 = t - row0 * 18;
    const int hy0 = ty0 + row0 - 1, hx0 = tx0 + col0 - 1;
    const int g0 = ((unsigned)hy0 < 128u && (unsigned)hx0 < 128u)
                       ? ((b << 14) + hy0 * 128 + hx0) : -1;
    const int t1 = t + 256, row1 = t1 / 18, col1 = t1 - row1 * 18;
    const int hy1 = ty0 + row1 - 1, hx1 = tx0 + col1 - 1;
    const int g1 = (t < 68 && (unsigned)hy1 < 128u && (unsigned)hx1 < 128u)
                       ? ((b << 14) + hy1 * 128 + hx1) : -1;

    for (int chunk = 0; chunk < 8; ++chunk) {
        __syncthreads();   // fcwl visible (chunk 0) / prior conv reads done
        for (int i = t; i < 1296; i += 256)
            dwl[i] = depw[(chunk * 16 + (i & 15)) * 81 + (i >> 4)];

#pragma unroll
        for (int half = 0; half < 2; ++half) {
            const int g = half ? g1 : g0;
            const int pix = half ? (256 + t) : t;
            if (half && t >= 68) break;
            float fo[9][4];
#pragma unroll
            for (int ii = 0; ii < 9; ++ii) {
                const float bv = (g >= 0) ? fcbl[ii] : 0.f;
                fo[ii][0] = bv; fo[ii][1] = bv; fo[ii][2] = bv; fo[ii][3] = bv;
            }
            if (g >= 0) {
                const uint2* qp = (const uint2*)(qkv + (size_t)g * 384 + chunk * 4);
#pragma unroll
                for (int e = 0; e < 12; ++e) {
                    const uint2 q = qp[e * 8];
                    const float f0 = blo(q.x), f1 = bhi(q.x);
                    const float f2 = blo(q.y), f3 = bhi(q.y);
#pragma unroll
                    for (int ii = 0; ii < 9; ++ii) {
                        const float wv = fcwl[ii * 12 + e];
                        fo[ii][0] += wv * f0; fo[ii][1] += wv * f1;
                        fo[ii][2] += wv * f2; fo[ii][3] += wv * f3;
                    }
                }
            }
#pragma unroll
            for (int ii = 0; ii < 9; ++ii)
#pragma unroll
                for (int dd = 0; dd < 4; ++dd)
                    fcl[(ii * 4 + dd) * 324 + pix] = fo[ii][dd];
        }
        __syncthreads();

        float4 accv[4];
#pragma unroll
        for (int dd = 0; dd < 4; ++dd) accv[dd] = make_float4(0.f, 0.f, 0.f, 0.f);
#pragma unroll
        for (int ii = 0; ii < 9; ++ii) {
#pragma unroll
            for (int kk = 0; kk < 9; ++kk) {
                const int ky = kk / 3, kx = kk - (kk / 3) * 3;
                const int hpix = (py + ky) * 18 + px + kx;
                const float4* dwp = (const float4*)&dwl[(ii * 9 + kk) * 16];
#pragma unroll
                for (int dd = 0; dd < 4; ++dd) {
                    const float f = fcl[(ii * 4 + dd) * 324 + hpix];
                    const float4 d4 = dwp[dd];
                    accv[dd].x += f * d4.x; accv[dd].y += f * d4.y;
                    accv[dd].z += f * d4.z; accv[dd].w += f * d4.w;
                }
            }
        }
#pragma unroll
        for (int dd = 0; dd < 4; ++dd) {
            const float av[4] = {accv[dd].x, accv[dd].y, accv[dd].z, accv[dd].w};
#pragma unroll
            for (int j = 0; j < 4; ++j) {
                const int oc = chunk * 16 + dd * 4 + j;
                ob[(size_t)oc << 14] += rate2 * (av[j] + depb[oc]);
            }
        }
    }
}

// ==================================================================
// FALLBACK PATH (ws too small): round-5 kernels, verbatim.
// ==================================================================
#define WS_W2  0
#define WS_B2  36864
#define WS_TOT 37152

__global__ __launch_bounds__(256) void k_prep_f(
    const float* __restrict__ qkv_w, const float* __restrict__ qkv_b,
    const float* __restrict__ fcw, const float* __restrict__ fcb,
    float* __restrict__ ws)
{
    const int idx = blockIdx.x * 256 + threadIdx.x;
    if (idx < WS_B2) {
        const int c = idx / 288, r = idx - c * 288, i = r >> 5, d = r & 31;
        float s = 0.f;
#pragma unroll
        for (int e = 0; e < 12; ++e)
            s += fcw[i * 12 + e] * qkv_w[c * 384 + e * 32 + d];
        ws[idx] = s;
    } else if (idx < WS_TOT) {
        const int r = idx - WS_B2, i = r >> 5, d = r & 31;
        float s = fcb[i];
#pragma unroll
        for (int e = 0; e < 12; ++e)
            s += fcw[i * 12 + e] * qkv_b[e * 32 + d];
        ws[idx] = s;
    }
}

__global__ __launch_bounds__(256) void k_attn_f(
    const float* __restrict__ x, const float* __restrict__ qw,
    const float* __restrict__ qb, const float* __restrict__ pw,
    const float* __restrict__ pb, const float* __restrict__ rpb,
    const float* __restrict__ r1, float* __restrict__ out)
{
    __shared__ ushort_t xw[8192];
    __shared__ float arena[8450];
    ushort_t* kvb = (ushort_t*)arena;
    const int t = threadIdx.x;
    const int b = blockIdx.x >> 8, wy = (blockIdx.x >> 4) & 15, wx = blockIdx.x & 15;
    const size_t xbase = ((size_t)b << 21) + (size_t)((wy * 8) * 128 + wx * 8);
    for (int i = t; i < 8192; i += 256) {
        const int c = i >> 6, p = i & 63;
        xw[i] = f2u(x[xbase + (size_t)c * 16384 + (p >> 3) * 128 + (p & 7)]);
    }
    __syncthreads();
    const int h = t >> 6, n = t & 63;
    float qa[32], ka[32], va[32];
#pragma unroll
    for (int cc = 0; cc < 32; ++cc) {
        qa[cc] = qb[h * 32 + cc];
        ka[cc] = qb[128 + h * 32 + cc];
        va[cc] = qb[256 + h * 32 + cc];
    }
    const float* wbase = qw + h * 32;
    for (int c = 0; c < 128; ++c) {
        const float xv = u2f(xw[c * 64 + n]);
        const float* wr = wbase + c * 384;
#pragma unroll
        for (int j = 0; j < 8; ++j) {
            const float4 aq = ((const float4*)wr)[j];
            const float4 ak = ((const float4*)(wr + 128))[j];
            const float4 av = ((const float4*)(wr + 256))[j];
            qa[4 * j + 0] += xv * aq.x; qa[4 * j + 1] += xv * aq.y;
            qa[4 * j + 2] += xv * aq.z; qa[4 * j + 3] += xv * aq.w;
            ka[4 * j + 0] += xv * ak.x; ka[4 * j + 1] += xv * ak.y;
            ka[4 * j + 2] += xv * ak.z; ka[4 * j + 3] += xv * ak.w;
            va[4 * j + 0] += xv * av.x; va[4 * j + 1] += xv * av.y;
            va[4 * j + 2] += xv * av.z; va[4 * j + 3] += xv * av.w;
        }
    }
#pragma unroll
    for (int cc = 0; cc < 32; ++cc) qa[cc] *= SCALE;
    uint_t* kv32 = (uint_t*)kvb;
#pragma unroll
    for (int j = 0; j < 16; ++j) {
        kv32[n * 66 + h * 16 + j] = pack2(ka[2 * j], ka[2 * j + 1]);
        kv32[4224 + n * 66 + h * 16 + j] = pack2(va[2 * j], va[2 * j + 1]);
    }
    __syncthreads();
    const int ry = n >> 3, rx = n & 7;
    float sar[64];
    float mx = -1e30f;
#pragma unroll
    for (int m = 0; m < 64; ++m) {
        const uint2* kr = (const uint2*)(kvb + m * 132 + h * 32);
        float s = 0.f;
#pragma unroll
        for (int j = 0; j < 8; ++j) {
            const uint2 u = kr[j];
            s += qa[4 * j + 0] * blo(u.x) + qa[4 * j + 1] * bhi(u.x)
               + qa[4 * j + 2] * blo(u.y) + qa[4 * j + 3] * bhi(u.y);
        }
        s += rpb[((ry - (m >> 3) + 7) * 15 + (rx - (m & 7) + 7)) * 4 + h];
        sar[m] = s;
        mx = fmaxf(mx, s);
    }
    float l = 0.f;
#pragma unroll
    for (int m = 0; m < 64; ++m) { const float e = __expf(sar[m] - mx); sar[m] = e; l += e; }
    const float inv = 1.f / l;
    float acc[32];
#pragma unroll
    for (int cc = 0; cc < 32; ++cc) acc[cc] = 0.f;
#pragma unroll
    for (int m = 0; m < 64; ++m) {
        const float pm = sar[m];
        const uint2* vr = (const uint2*)(kvb + 8448 + m * 132 + h * 32);
#pragma unroll
        for (int j = 0; j < 8; ++j) {
            const uint2 u = vr[j];
            acc[4 * j + 0] += pm * blo(u.x); acc[4 * j + 1] += pm * bhi(u.x);
            acc[4 * j + 2] += pm * blo(u.y); acc[4 * j + 3] += pm * bhi(u.y);
        }
    }
    __syncthreads();
#pragma unroll
    for (int cc = 0; cc < 32; ++cc) arena[n * 130 + h * 32 + cc] = acc[cc] * inv;
    __syncthreads();
    const int p = t & 63, jb = t >> 6;
    float aj[32];
#pragma unroll
    for (int jj = 0; jj < 32; ++jj) aj[jj] = pb[jb * 32 + jj];
    const float* xr = arena + p * 130;
    const float* pwb = pw + jb * 32;
    for (int c = 0; c < 128; ++c) {
        const float xv = xr[c];
        const float4* pr = (const float4*)(pwb + c * 128);
#pragma unroll
        for (int j = 0; j < 8; ++j) {
            const float4 w4 = pr[j];
            aj[4 * j + 0] += xv * w4.x; aj[4 * j + 1] += xv * w4.y;
            aj[4 * j + 2] += xv * w4.z; aj[4 * j + 3] += xv * w4.w;
        }
    }
    const float rate1 = r1[0];
    const int oy = wy * 8 + (p >> 3), ox = wx * 8 + (p & 7);
    float* ob = out + ((size_t)b << 21) + (size_t)(oy * 128 + ox);
#pragma unroll
    for (int jj = 0; jj < 32; ++jj)
        ob[(size_t)(jb * 32 + jj) << 14] = rate1 * aj[jj];
}

__global__ __launch_bounds__(256) void k_conv_f(
    const float* __restrict__ x, const float* __restrict__ ws,
    const float* __restrict__ depw, const float* __restrict__ depb,
    const float* __restrict__ r2, float* __restrict__ out)
{
    __shared__ float arena[12960];
    __shared__ float b2s[36];
    float* w2l = arena;
    ushort_t* xl = (ushort_t*)(arena + 4608);
    float* fcl = arena;
    float* dwl = arena + 11664;
    const int t = threadIdx.x;
    const int b = blockIdx.x >> 6, tile = blockIdx.x & 63;
    const int ty0 = (tile >> 3) << 4, tx0 = (tile & 7) << 4;
    const size_t xbase = ((size_t)b << 21);
    const float rate2 = r2[0];
    const int py = t >> 4, px = t & 15;
    float* ob = out + ((size_t)b << 21) + (size_t)((ty0 + py) * 128 + (tx0 + px));
    const int r0 = t / 18, c0 = t - r0 * 18;
    const bool ok0 = ((unsigned)(ty0 + r0 - 1) < 128u) && ((unsigned)(tx0 + c0 - 1) < 128u);
    const int t1 = 256 + t, r1i = t1 / 18, c1 = t1 - r1i * 18;
    const bool ok1 = (t < 68) && ((unsigned)(ty0 + r1i - 1) < 128u) && ((unsigned)(tx0 + c1 - 1) < 128u);
    for (int chunk = 0; chunk < 8; ++chunk) {
        __syncthreads();
        for (int i = t; i < 4608; i += 256) {
            const int c = i / 36, r = i - c * 36;
            w2l[i] = ws[WS_W2 + c * 288 + (r >> 2) * 32 + chunk * 4 + (r & 3)];
        }
        if (t < 36) b2s[t] = ws[WS_B2 + (t >> 2) * 32 + chunk * 4 + (t & 3)];
        __syncthreads();
        float fca[2][36];
#pragma unroll
        for (int r = 0; r < 36; ++r) { fca[0][r] = b2s[r]; fca[1][r] = b2s[r]; }
        for (int cs = 0; cs < 8; ++cs) {
            if (cs) __syncthreads();
            for (int i = t; i < 5184; i += 256) {
                const int cc = i / 324, pp = i - cc * 324;
                const int row = pp / 18, col = pp - row * 18;
                const int hy = ty0 + row - 1, hx = tx0 + col - 1;
                ushort_t v = 0;
                if ((unsigned)hy < 128u && (unsigned)hx < 128u)
                    v = f2u(x[xbase + (size_t)(cs * 16 + cc) * 16384 + hy * 128 + hx]);
                xl[i] = v;
            }
            __syncthreads();
#pragma unroll 4
            for (int cc = 0; cc < 16; ++cc) {
                const float xv0 = u2f(xl[cc * 324 + t]);
                const float xv1 = (t < 68) ? u2f(xl[cc * 324 + 256 + t]) : 0.f;
                const float* wr = w2l + (cs * 16 + cc) * 36;
#pragma unroll
                for (int r = 0; r < 36; r += 4) {
                    const float4 w4 = *(const float4*)(wr + r);
                    fca[0][r + 0] += xv0 * w4.x; fca[0][r + 1] += xv0 * w4.y;
                    fca[0][r + 2] += xv0 * w4.z; fca[0][r + 3] += xv0 * w4.w;
                    fca[1][r + 0] += xv1 * w4.x; fca[1][r + 1] += xv1 * w4.y;
                    fca[1][r + 2] += xv1 * w4.z; fca[1][r + 3] += xv1 * w4.w;
                }
            }
        }
        __syncthreads();
#pragma unroll
        for (int r = 0; r < 36; ++r) {
            fcl[r * 324 + t] = ok0 ? fca[0][r] : 0.f;
            if (t < 68) fcl[r * 324 + 256 + t] = ok1 ? fca[1][r] : 0.f;
        }
        for (int i = t; i < 1296; i += 256) {
            const int kk = i >> 4, ocl = i & 15;
            dwl[i] = depw[(chunk * 16 + ocl) * 81 + kk];
        }
        __syncthreads();
        float4 accv[4];
#pragma unroll
        for (int dd = 0; dd < 4; ++dd) accv[dd] = make_float4(0.f, 0.f, 0.f, 0.f);
#pragma unroll
        for (int ii = 0; ii < 9; ++ii) {
#pragma unroll
            for (int kk = 0; kk < 9; ++kk) {
                const int ky = kk / 3, kx = kk - (kk / 3) * 3;
                const int hpix = (py + ky) * 18 + px + kx;
                const float4* dwp = (const float4*)&dwl[(ii * 9 + kk) * 16];
#pragma unroll
                for (int dd = 0; dd < 4; ++dd) {
                    const float f = fcl[(ii * 4 + dd) * 324 + hpix];
                    const float4 d4 = dwp[dd];
                    accv[dd].x += f * d4.x; accv[dd].y += f * d4.y;
                    accv[dd].z += f * d4.z; accv[dd].w += f * d4.w;
                }
            }
        }
#pragma unroll
        for (int dd = 0; dd < 4; ++dd) {
            const float av[4] = {accv[dd].x, accv[dd].y, accv[dd].z, accv[dd].w};
#pragma unroll
            for (int j = 0; j < 4; ++j) {
                const int oc = chunk * 16 + dd * 4 + j;
                ob[(size_t)oc << 14] += rate2 * (av[j] + depb[oc]);
            }
        }
    }
}

// ------------------------------------------------------------------
extern "C" void kernel_launch(void* const* d_in, const int* in_sizes, int n_in,
                              void* d_out, int out_size, void* d_ws, size_t ws_size,
                              hipStream_t stream) {
    (void)in_sizes; (void)n_in; (void)out_size;
    const float* x      = (const float*)d_in[0];
    const float* qkv_w  = (const float*)d_in[1];
    const float* qkv_b  = (const float*)d_in[2];
    const float* proj_w = (const float*)d_in[3];
    const float* proj_b = (const float*)d_in[4];
    const float* rpb    = (const float*)d_in[5];
    const float* fc_w   = (const float*)d_in[6];
    const float* fc_b   = (const float*)d_in[7];
    const float* dep_w  = (const float*)d_in[8];
    const float* dep_b  = (const float*)d_in[9];
    const float* rate1  = (const float*)d_in[10];
    const float* rate2  = (const float*)d_in[11];
    float* out = (float*)d_out;

    if (ws_size >= (size_t)131072 * 384 * 2) {
        ushort_t* qkv = (ushort_t*)d_ws;   // 96 MB bf16
        k_qqkv<<<dim3(12288), dim3(256), 0, stream>>>(x, qkv_w, qkv_b, qkv);
        k_attn2<<<dim3(2048), dim3(256), 0, stream>>>(qkv, proj_w, proj_b,
                                                      rpb, rate1, out);
        k_conv2<<<dim3(512), dim3(256), 0, stream>>>(qkv, fc_w, fc_b, dep_w,
                                                     dep_b, rate2, out);
    } else {
        float* wsf = (float*)d_ws;         // 148.6 KB
        k_prep_f<<<dim3(146), dim3(256), 0, stream>>>(qkv_w, qkv_b, fc_w, fc_b, wsf);
        k_attn_f<<<dim3(2048), dim3(256), 0, stream>>>(x, qkv_w, qkv_b, proj_w,
                                                       proj_b, rpb, rate1, out);
        k_conv_f<<<dim3(512), dim3(256), 0, stream>>>(x, wsf, dep_w, dep_b,
                                                      rate2, out);
    }
}

// Round 3
// 862.488 us; speedup vs baseline: 1.4204x; 1.4204x over previous
//
#include <hip/hip_runtime.h>

typedef unsigned short ushort_t;
typedef unsigned int uint_t;

#define SCALE 0.17677669529663687f

__device__ __forceinline__ float blo(uint_t u) { return __uint_as_float(u << 16); }
__device__ __forceinline__ float bhi(uint_t u) { return __uint_as_float(u & 0xffff0000u); }
__device__ __forceinline__ float u2f(ushort_t u) { return __uint_as_float(((uint_t)u) << 16); }
// fp32 -> bf16 (RNE), finite inputs
__device__ __forceinline__ ushort_t f2u(float f) {
    const uint_t x = __float_as_uint(f);
    return (ushort_t)((x + 0x7fffu + ((x >> 16) & 1u)) >> 16);
}
__device__ __forceinline__ uint_t pack2(float a, float b) {
    return (uint_t)f2u(a) | ((uint_t)f2u(b) << 16);
}

__device__ __forceinline__ float dot8(const float* qa, uint4 u) {
    return qa[0] * blo(u.x) + qa[1] * bhi(u.x) + qa[2] * blo(u.y) + qa[3] * bhi(u.y)
         + qa[4] * blo(u.z) + qa[5] * bhi(u.z) + qa[6] * blo(u.w) + qa[7] * bhi(u.w);
}
__device__ __forceinline__ void pv8(float* a, float e, uint4 u) {
    a[0] += e * blo(u.x); a[1] += e * bhi(u.x); a[2] += e * blo(u.y); a[3] += e * bhi(u.y);
    a[4] += e * blo(u.z); a[5] += e * bhi(u.z); a[6] += e * blo(u.w); a[7] += e * bhi(u.w);
}

// ==================================================================
// MAIN PATH: qkv materialized in ws as bf16 [p][j], p=131072, j=384.
// Requires ws_size >= 96 MB.
// ==================================================================

// ------------------------------------------------------------------
// k_qqkv: qkv[p, j] = bf16( sum_c x[b,c,p] * qkv_w[c,j] + qkv_b[j] )
// 64 pixels x 64 j per block; K=128 fully staged in LDS (fp32).
// ------------------------------------------------------------------
__global__ __launch_bounds__(256) void k_qqkv(
    const float* __restrict__ x, const float* __restrict__ w,
    const float* __restrict__ wb, ushort_t* __restrict__ qkv)
{
    __shared__ float a_lds[128 * 64];   // [c][p]
    __shared__ float b_lds[128 * 64];   // [c][j]
    const int t = threadIdx.x;
    const int tileP = blockIdx.x & 2047;       // 2048 pixel tiles of 64
    const int j0 = (blockIdx.x >> 11) * 64;    // 6 j tiles
    const int p0 = tileP * 64;
    const int b = p0 >> 14;                    // HW = 16384
    const int rem = p0 & 16383;
    const float* xb = x + ((size_t)b << 21) + rem;

    for (int i = t; i < 8192; i += 256) {
        const int c = i >> 6, p = i & 63;
        a_lds[i] = xb[c * 16384 + p];
    }
    for (int i = t; i < 8192; i += 256) {
        const int c = i >> 6, jj = i & 63;
        b_lds[i] = w[c * 384 + j0 + jj];
    }
    __syncthreads();

    const int tp = t >> 4, tj = t & 15;
    float acc[4][4];
#pragma unroll
    for (int i = 0; i < 4; ++i)
#pragma unroll
        for (int j = 0; j < 4; ++j) acc[i][j] = 0.f;

#pragma unroll 4
    for (int k = 0; k < 128; ++k) {
        const float4 av = *(const float4*)&a_lds[k * 64 + tp * 4];
        const float4 bv = *(const float4*)&b_lds[k * 64 + tj * 4];
        acc[0][0] += av.x * bv.x; acc[0][1] += av.x * bv.y; acc[0][2] += av.x * bv.z; acc[0][3] += av.x * bv.w;
        acc[1][0] += av.y * bv.x; acc[1][1] += av.y * bv.y; acc[1][2] += av.y * bv.z; acc[1][3] += av.y * bv.w;
        acc[2][0] += av.z * bv.x; acc[2][1] += av.z * bv.y; acc[2][2] += av.z * bv.z; acc[2][3] += av.z * bv.w;
        acc[3][0] += av.w * bv.x; acc[3][1] += av.w * bv.y; acc[3][2] += av.w * bv.z; acc[3][3] += av.w * bv.w;
    }

    float bb[4];
#pragma unroll
    for (int jj = 0; jj < 4; ++jj) bb[jj] = wb[j0 + tj * 4 + jj];
#pragma unroll
    for (int i = 0; i < 4; ++i) {
        uint2 o;
        o.x = pack2(acc[i][0] + bb[0], acc[i][1] + bb[1]);
        o.y = pack2(acc[i][2] + bb[2], acc[i][3] + bb[3]);
        *(uint2*)&qkv[(size_t)(p0 + tp * 4 + i) * 384 + j0 + tj * 4] = o;
    }
}

// ------------------------------------------------------------------
// k_attn2: per 8x8 window. k/v staged from qkv into LDS (bf16,
// 16B-aligned stride-68-uint rows), q from qkv into regs; FUSED
// online-softmax attention (no score array); rpb staged in LDS;
// proj; OVERWRITE out = rate1 * xa (fp32).
// Thread (h = t>>6, n = t&63).
// ------------------------------------------------------------------
__global__ __launch_bounds__(256, 4) void k_attn2(
    const ushort_t* __restrict__ qkv, const float* __restrict__ pw,
    const float* __restrict__ pb, const float* __restrict__ rpb,
    const float* __restrict__ r1, float* __restrict__ out)
{
    // [0, 8704) uints: k rows (64 x 68) then v rows (64 x 68), bf16 pairs.
    // overlapped later by xa (64 x 130 floats = 8320 < 8704).
    // [8704, 9604) floats: rpb table (225 x 4).
    __shared__ float arena[9604];
    uint_t* kv32 = (uint_t*)arena;
    float* rpbl = arena + 8704;
    const int t = threadIdx.x;
    const int b = blockIdx.x >> 8, wy = (blockIdx.x >> 4) & 15, wx = blockIdx.x & 15;
    const int prow0 = (b << 14) + (wy * 8) * 128 + wx * 8;
    const uint_t* qkvu = (const uint_t*)qkv;

    // stage k (j 128..255) and v (j 256..383): per m, 64 uints each
    for (int i = t; i < 4096; i += 256) {
        const int m = i >> 6, u = i & 63;
        const size_t pr = (size_t)(prow0 + (m >> 3) * 128 + (m & 7)) * 192;
        kv32[m * 68 + u]        = qkvu[pr + 64 + u];
        kv32[4352 + m * 68 + u] = qkvu[pr + 128 + u];
    }
    for (int i = t; i < 900; i += 256) rpbl[i] = rpb[i];

    const int h = t >> 6, n = t & 63;
    const size_t pq = (size_t)(prow0 + (n >> 3) * 128 + (n & 7)) * 192;
    float qa[32];
    const uint_t* qrow = qkvu + pq + h * 16;
#pragma unroll
    for (int j = 0; j < 16; ++j) {
        const uint_t u = qrow[j];
        qa[2 * j]     = blo(u) * SCALE;
        qa[2 * j + 1] = bhi(u) * SCALE;
    }
    __syncthreads();

    const int ry = n >> 3, rx = n & 7;
    const float* rpbl_t = rpbl + h;
    const int rbase = (ry + 7) * 15 + (rx + 7);

    const uint_t* kbase = kv32 + h * 16;
    const uint_t* vbase = kv32 + 4352 + h * 16;

    float mx = -1e30f, l = 0.f;
    float acc[32];
#pragma unroll
    for (int cc = 0; cc < 32; ++cc) acc[cc] = 0.f;

#pragma unroll 4
    for (int m = 0; m < 64; ++m) {
        const uint4* kr = (const uint4*)(kbase + m * 68);
        const uint4 k0 = kr[0], k1 = kr[1], k2 = kr[2], k3 = kr[3];
        float s = (dot8(qa, k0) + dot8(qa + 8, k1))
                + (dot8(qa + 16, k2) + dot8(qa + 24, k3));
        s += rpbl_t[4 * (rbase - (m >> 3) * 15 - (m & 7))];
        if (s > mx) {
            const float sc = __expf(mx - s);
            mx = s;
            l *= sc;
#pragma unroll
            for (int cc = 0; cc < 32; ++cc) acc[cc] *= sc;
        }
        const float e = __expf(s - mx);
        l += e;
        const uint4* vr = (const uint4*)(vbase + m * 68);
        const uint4 v0 = vr[0], v1 = vr[1], v2 = vr[2], v3 = vr[3];
        pv8(acc, e, v0); pv8(acc + 8, e, v1);
        pv8(acc + 16, e, v2); pv8(acc + 24, e, v3);
    }
    const float inv = 1.f / l;

    __syncthreads();   // all k/v reads done
#pragma unroll
    for (int cc = 0; cc < 32; ++cc) arena[n * 130 + h * 32 + cc] = acc[cc] * inv;
    __syncthreads();

    // proj: out = rate1 * (xa @ proj_w + proj_b)
    const int p = t & 63, jb = t >> 6;
    float aj[32];
#pragma unroll
    for (int jj = 0; jj < 32; ++jj) aj[jj] = pb[jb * 32 + jj];
    const float* xr = arena + p * 130;
    const float* pwb = pw + jb * 32;
    for (int c = 0; c < 128; ++c) {
        const float xv = xr[c];
        const float4* pr = (const float4*)(pwb + c * 128);
#pragma unroll
        for (int j = 0; j < 8; ++j) {
            const float4 w4 = pr[j];
            aj[4 * j + 0] += xv * w4.x; aj[4 * j + 1] += xv * w4.y;
            aj[4 * j + 2] += xv * w4.z; aj[4 * j + 3] += xv * w4.w;
        }
    }
    const float rate1 = r1[0];
    const int oy = wy * 8 + (p >> 3), ox = wx * 8 + (p & 7);
    float* ob = out + ((size_t)b << 21) + (size_t)(oy * 128 + ox);
#pragma unroll
    for (int jj = 0; jj < 32; ++jj)
        ob[(size_t)(jb * 32 + jj) << 14] = rate1 * aj[jj];
}

// ------------------------------------------------------------------
// k_conv2: per 16x16 tile, 8 chunks of 4 d.  f_c[i,d] at each 18x18
// halo pixel from materialized qkv (12 MACs per output), zero outside
// the image; then the 81-tap grouped conv; RMW out += rate2*(conv+db).
// ------------------------------------------------------------------
__global__ __launch_bounds__(256) void k_conv2(
    const ushort_t* __restrict__ qkv, const float* __restrict__ fcw,
    const float* __restrict__ fcb, const float* __restrict__ depw,
    const float* __restrict__ depb, const float* __restrict__ r2,
    float* __restrict__ out)
{
    __shared__ float fcl[11664];    // [(ii*4+dd)*324 + pix]
    __shared__ __align__(16) float dwl[1296];   // [kk81][16 oc-in-chunk]
    __shared__ float fcwl[108];
    __shared__ float fcbl[9];

    const int t = threadIdx.x;
    const int b = blockIdx.x >> 6, tile = blockIdx.x & 63;
    const int ty0 = (tile >> 3) << 4, tx0 = (tile & 7) << 4;
    if (t < 108) fcwl[t] = fcw[t];
    if (t < 9)   fcbl[t] = fcb[t];
    const float rate2 = r2[0];
    const int py = t >> 4, px = t & 15;
    float* ob = out + ((size_t)b << 21) + (size_t)((ty0 + py) * 128 + (tx0 + px));

    // this thread's halo pixels: pix0 = t, pix1 = 256+t (t<68)
    const int row0 = t / 18, col0 = t - row0 * 18;
    const int hy0 = ty0 + row0 - 1, hx0 = tx0 + col0 - 1;
    const int g0 = ((unsigned)hy0 < 128u && (unsigned)hx0 < 128u)
                       ? ((b << 14) + hy0 * 128 + hx0) : -1;
    const int t1 = t + 256, row1 = t1 / 18, col1 = t1 - row1 * 18;
    const int hy1 = ty0 + row1 - 1, hx1 = tx0 + col1 - 1;
    const int g1 = (t < 68 && (unsigned)hy1 < 128u && (unsigned)hx1 < 128u)
                       ? ((b << 14) + hy1 * 128 + hx1) : -1;

    for (int chunk = 0; chunk < 8; ++chunk) {
        __syncthreads();   // fcwl visible (chunk 0) / prior conv reads done
        for (int i = t; i < 1296; i += 256)
            dwl[i] = depw[(chunk * 16 + (i & 15)) * 81 + (i >> 4)];

#pragma unroll
        for (int half = 0; half < 2; ++half) {
            const int g = half ? g1 : g0;
            const int pix = half ? (256 + t) : t;
            if (half && t >= 68) break;
            float fo[9][4];
#pragma unroll
            for (int ii = 0; ii < 9; ++ii) {
                const float bv = (g >= 0) ? fcbl[ii] : 0.f;
                fo[ii][0] = bv; fo[ii][1] = bv; fo[ii][2] = bv; fo[ii][3] = bv;
            }
            if (g >= 0) {
                const uint2* qp = (const uint2*)(qkv + (size_t)g * 384 + chunk * 4);
#pragma unroll
                for (int e = 0; e < 12; ++e) {
                    const uint2 q = qp[e * 8];
                    const float f0 = blo(q.x), f1 = bhi(q.x);
                    const float f2 = blo(q.y), f3 = bhi(q.y);
#pragma unroll
                    for (int ii = 0; ii < 9; ++ii) {
                        const float wv = fcwl[ii * 12 + e];
                        fo[ii][0] += wv * f0; fo[ii][1] += wv * f1;
                        fo[ii][2] += wv * f2; fo[ii][3] += wv * f3;
                    }
                }
            }
#pragma unroll
            for (int ii = 0; ii < 9; ++ii)
#pragma unroll
                for (int dd = 0; dd < 4; ++dd)
                    fcl[(ii * 4 + dd) * 324 + pix] = fo[ii][dd];
        }
        __syncthreads();

        float4 accv[4];
#pragma unroll
        for (int dd = 0; dd < 4; ++dd) accv[dd] = make_float4(0.f, 0.f, 0.f, 0.f);
#pragma unroll
        for (int ii = 0; ii < 9; ++ii) {
#pragma unroll
            for (int kk = 0; kk < 9; ++kk) {
                const int ky = kk / 3, kx = kk - (kk / 3) * 3;
                const int hpix = (py + ky) * 18 + px + kx;
                const float4* dwp = (const float4*)&dwl[(ii * 9 + kk) * 16];
#pragma unroll
                for (int dd = 0; dd < 4; ++dd) {
                    const float f = fcl[(ii * 4 + dd) * 324 + hpix];
                    const float4 d4 = dwp[dd];
                    accv[dd].x += f * d4.x; accv[dd].y += f * d4.y;
                    accv[dd].z += f * d4.z; accv[dd].w += f * d4.w;
                }
            }
        }
#pragma unroll
        for (int dd = 0; dd < 4; ++dd) {
            const float av[4] = {accv[dd].x, accv[dd].y, accv[dd].z, accv[dd].w};
#pragma unroll
            for (int j = 0; j < 4; ++j) {
                const int oc = chunk * 16 + dd * 4 + j;
                ob[(size_t)oc << 14] += rate2 * (av[j] + depb[oc]);
            }
        }
    }
}

// ==================================================================
// FALLBACK PATH (ws too small): round-5 kernels, verbatim.
// ==================================================================
#define WS_W2  0
#define WS_B2  36864
#define WS_TOT 37152

__global__ __launch_bounds__(256) void k_prep_f(
    const float* __restrict__ qkv_w, const float* __restrict__ qkv_b,
    const float* __restrict__ fcw, const float* __restrict__ fcb,
    float* __restrict__ ws)
{
    const int idx = blockIdx.x * 256 + threadIdx.x;
    if (idx < WS_B2) {
        const int c = idx / 288, r = idx - c * 288, i = r >> 5, d = r & 31;
        float s = 0.f;
#pragma unroll
        for (int e = 0; e < 12; ++e)
            s += fcw[i * 12 + e] * qkv_w[c * 384 + e * 32 + d];
        ws[idx] = s;
    } else if (idx < WS_TOT) {
        const int r = idx - WS_B2, i = r >> 5, d = r & 31;
        float s = fcb[i];
#pragma unroll
        for (int e = 0; e < 12; ++e)
            s += fcw[i * 12 + e] * qkv_b[e * 32 + d];
        ws[idx] = s;
    }
}

__global__ __launch_bounds__(256) void k_attn_f(
    const float* __restrict__ x, const float* __restrict__ qw,
    const float* __restrict__ qb, const float* __restrict__ pw,
    const float* __restrict__ pb, const float* __restrict__ rpb,
    const float* __restrict__ r1, float* __restrict__ out)
{
    __shared__ ushort_t xw[8192];
    __shared__ float arena[8450];
    ushort_t* kvb = (ushort_t*)arena;
    const int t = threadIdx.x;
    const int b = blockIdx.x >> 8, wy = (blockIdx.x >> 4) & 15, wx = blockIdx.x & 15;
    const size_t xbase = ((size_t)b << 21) + (size_t)((wy * 8) * 128 + wx * 8);
    for (int i = t; i < 8192; i += 256) {
        const int c = i >> 6, p = i & 63;
        xw[i] = f2u(x[xbase + (size_t)c * 16384 + (p >> 3) * 128 + (p & 7)]);
    }
    __syncthreads();
    const int h = t >> 6, n = t & 63;
    float qa[32], ka[32], va[32];
#pragma unroll
    for (int cc = 0; cc < 32; ++cc) {
        qa[cc] = qb[h * 32 + cc];
        ka[cc] = qb[128 + h * 32 + cc];
        va[cc] = qb[256 + h * 32 + cc];
    }
    const float* wbase = qw + h * 32;
    for (int c = 0; c < 128; ++c) {
        const float xv = u2f(xw[c * 64 + n]);
        const float* wr = wbase + c * 384;
#pragma unroll
        for (int j = 0; j < 8; ++j) {
            const float4 aq = ((const float4*)wr)[j];
            const float4 ak = ((const float4*)(wr + 128))[j];
            const float4 av = ((const float4*)(wr + 256))[j];
            qa[4 * j + 0] += xv * aq.x; qa[4 * j + 1] += xv * aq.y;
            qa[4 * j + 2] += xv * aq.z; qa[4 * j + 3] += xv * aq.w;
            ka[4 * j + 0] += xv * ak.x; ka[4 * j + 1] += xv * ak.y;
            ka[4 * j + 2] += xv * ak.z; ka[4 * j + 3] += xv * ak.w;
            va[4 * j + 0] += xv * av.x; va[4 * j + 1] += xv * av.y;
            va[4 * j + 2] += xv * av.z; va[4 * j + 3] += xv * av.w;
        }
    }
#pragma unroll
    for (int cc = 0; cc < 32; ++cc) qa[cc] *= SCALE;
    uint_t* kv32 = (uint_t*)kvb;
#pragma unroll
    for (int j = 0; j < 16; ++j) {
        kv32[n * 66 + h * 16 + j] = pack2(ka[2 * j], ka[2 * j + 1]);
        kv32[4224 + n * 66 + h * 16 + j] = pack2(va[2 * j], va[2 * j + 1]);
    }
    __syncthreads();
    const int ry = n >> 3, rx = n & 7;
    float sar[64];
    float mx = -1e30f;
#pragma unroll
    for (int m = 0; m < 64; ++m) {
        const uint2* kr = (const uint2*)(kvb + m * 132 + h * 32);
        float s = 0.f;
#pragma unroll
        for (int j = 0; j < 8; ++j) {
            const uint2 u = kr[j];
            s += qa[4 * j + 0] * blo(u.x) + qa[4 * j + 1] * bhi(u.x)
               + qa[4 * j + 2] * blo(u.y) + qa[4 * j + 3] * bhi(u.y);
        }
        s += rpb[((ry - (m >> 3) + 7) * 15 + (rx - (m & 7) + 7)) * 4 + h];
        sar[m] = s;
        mx = fmaxf(mx, s);
    }
    float l = 0.f;
#pragma unroll
    for (int m = 0; m < 64; ++m) { const float e = __expf(sar[m] - mx); sar[m] = e; l += e; }
    const float inv = 1.f / l;
    float acc[32];
#pragma unroll
    for (int cc = 0; cc < 32; ++cc) acc[cc] = 0.f;
#pragma unroll
    for (int m = 0; m < 64; ++m) {
        const float pm = sar[m];
        const uint2* vr = (const uint2*)(kvb + 8448 + m * 132 + h * 32);
#pragma unroll
        for (int j = 0; j < 8; ++j) {
            const uint2 u = vr[j];
            acc[4 * j + 0] += pm * blo(u.x); acc[4 * j + 1] += pm * bhi(u.x);
            acc[4 * j + 2] += pm * blo(u.y); acc[4 * j + 3] += pm * bhi(u.y);
        }
    }
    __syncthreads();
#pragma unroll
    for (int cc = 0; cc < 32; ++cc) arena[n * 130 + h * 32 + cc] = acc[cc] * inv;
    __syncthreads();
    const int p = t & 63, jb = t >> 6;
    float aj[32];
#pragma unroll
    for (int jj = 0; jj < 32; ++jj) aj[jj] = pb[jb * 32 + jj];
    const float* xr = arena + p * 130;
    const float* pwb = pw + jb * 32;
    for (int c = 0; c < 128; ++c) {
        const float xv = xr[c];
        const float4* pr = (const float4*)(pwb + c * 128);
#pragma unroll
        for (int j = 0; j < 8; ++j) {
            const float4 w4 = pr[j];
            aj[4 * j + 0] += xv * w4.x; aj[4 * j + 1] += xv * w4.y;
            aj[4 * j + 2] += xv * w4.z; aj[4 * j + 3] += xv * w4.w;
        }
    }
    const float rate1 = r1[0];
    const int oy = wy * 8 + (p >> 3), ox = wx * 8 + (p & 7);
    float* ob = out + ((size_t)b << 21) + (size_t)(oy * 128 + ox);
#pragma unroll
    for (int jj = 0; jj < 32; ++jj)
        ob[(size_t)(jb * 32 + jj) << 14] = rate1 * aj[jj];
}

__global__ __launch_bounds__(256) void k_conv_f(
    const float* __restrict__ x, const float* __restrict__ ws,
    const float* __restrict__ depw, const float* __restrict__ depb,
    const float* __restrict__ r2, float* __restrict__ out)
{
    __shared__ float arena[12960];
    __shared__ float b2s[36];
    float* w2l = arena;
    ushort_t* xl = (ushort_t*)(arena + 4608);
    float* fcl = arena;
    float* dwl = arena + 11664;
    const int t = threadIdx.x;
    const int b = blockIdx.x >> 6, tile = blockIdx.x & 63;
    const int ty0 = (tile >> 3) << 4, tx0 = (tile & 7) << 4;
    const size_t xbase = ((size_t)b << 21);
    const float rate2 = r2[0];
    const int py = t >> 4, px = t & 15;
    float* ob = out + ((size_t)b << 21) + (size_t)((ty0 + py) * 128 + (tx0 + px));
    const int r0 = t / 18, c0 = t - r0 * 18;
    const bool ok0 = ((unsigned)(ty0 + r0 - 1) < 128u) && ((unsigned)(tx0 + c0 - 1) < 128u);
    const int t1 = 256 + t, r1i = t1 / 18, c1 = t1 - r1i * 18;
    const bool ok1 = (t < 68) && ((unsigned)(ty0 + r1i - 1) < 128u) && ((unsigned)(tx0 + c1 - 1) < 128u);
    for (int chunk = 0; chunk < 8; ++chunk) {
        __syncthreads();
        for (int i = t; i < 4608; i += 256) {
            const int c = i / 36, r = i - c * 36;
            w2l[i] = ws[WS_W2 + c * 288 + (r >> 2) * 32 + chunk * 4 + (r & 3)];
        }
        if (t < 36) b2s[t] = ws[WS_B2 + (t >> 2) * 32 + chunk * 4 + (t & 3)];
        __syncthreads();
        float fca[2][36];
#pragma unroll
        for (int r = 0; r < 36; ++r) { fca[0][r] = b2s[r]; fca[1][r] = b2s[r]; }
        for (int cs = 0; cs < 8; ++cs) {
            if (cs) __syncthreads();
            for (int i = t; i < 5184; i += 256) {
                const int cc = i / 324, pp = i - cc * 324;
                const int row = pp / 18, col = pp - row * 18;
                const int hy = ty0 + row - 1, hx = tx0 + col - 1;
                ushort_t v = 0;
                if ((unsigned)hy < 128u && (unsigned)hx < 128u)
                    v = f2u(x[xbase + (size_t)(cs * 16 + cc) * 16384 + hy * 128 + hx]);
                xl[i] = v;
            }
            __syncthreads();
#pragma unroll 4
            for (int cc = 0; cc < 16; ++cc) {
                const float xv0 = u2f(xl[cc * 324 + t]);
                const float xv1 = (t < 68) ? u2f(xl[cc * 324 + 256 + t]) : 0.f;
                const float* wr = w2l + (cs * 16 + cc) * 36;
#pragma unroll
                for (int r = 0; r < 36; r += 4) {
                    const float4 w4 = *(const float4*)(wr + r);
                    fca[0][r + 0] += xv0 * w4.x; fca[0][r + 1] += xv0 * w4.y;
                    fca[0][r + 2] += xv0 * w4.z; fca[0][r + 3] += xv0 * w4.w;
                    fca[1][r + 0] += xv1 * w4.x; fca[1][r + 1] += xv1 * w4.y;
                    fca[1][r + 2] += xv1 * w4.z; fca[1][r + 3] += xv1 * w4.w;
                }
            }
        }
        __syncthreads();
#pragma unroll
        for (int r = 0; r < 36; ++r) {
            fcl[r * 324 + t] = ok0 ? fca[0][r] : 0.f;
            if (t < 68) fcl[r * 324 + 256 + t] = ok1 ? fca[1][r] : 0.f;
        }
        for (int i = t; i < 1296; i += 256) {
            const int kk = i >> 4, ocl = i & 15;
            dwl[i] = depw[(chunk * 16 + ocl) * 81 + kk];
        }
        __syncthreads();
        float4 accv[4];
#pragma unroll
        for (int dd = 0; dd < 4; ++dd) accv[dd] = make_float4(0.f, 0.f, 0.f, 0.f);
#pragma unroll
        for (int ii = 0; ii < 9; ++ii) {
#pragma unroll
            for (int kk = 0; kk < 9; ++kk) {
                const int ky = kk / 3, kx = kk - (kk / 3) * 3;
                const int hpix = (py + ky) * 18 + px + kx;
                const float4* dwp = (const float4*)&dwl[(ii * 9 + kk) * 16];
#pragma unroll
                for (int dd = 0; dd < 4; ++dd) {
                    const float f = fcl[(ii * 4 + dd) * 324 + hpix];
                    const float4 d4 = dwp[dd];
                    accv[dd].x += f * d4.x; accv[dd].y += f * d4.y;
                    accv[dd].z += f * d4.z; accv[dd].w += f * d4.w;
                }
            }
        }
#pragma unroll
        for (int dd = 0; dd < 4; ++dd) {
            const float av[4] = {accv[dd].x, accv[dd].y, accv[dd].z, accv[dd].w};
#pragma unroll
            for (int j = 0; j < 4; ++j) {
                const int oc = chunk * 16 + dd * 4 + j;
                ob[(size_t)oc << 14] += rate2 * (av[j] + depb[oc]);
            }
        }
    }
}

// ------------------------------------------------------------------
extern "C" void kernel_launch(void* const* d_in, const int* in_sizes, int n_in,
                              void* d_out, int out_size, void* d_ws, size_t ws_size,
                              hipStream_t stream) {
    (void)in_sizes; (void)n_in; (void)out_size;
    const float* x      = (const float*)d_in[0];
    const float* qkv_w  = (const float*)d_in[1];
    const float* qkv_b  = (const float*)d_in[2];
    const float* proj_w = (const float*)d_in[3];
    const float* proj_b = (const float*)d_in[4];
    const float* rpb    = (const float*)d_in[5];
    const float* fc_w   = (const float*)d_in[6];
    const float* fc_b   = (const float*)d_in[7];
    const float* dep_w  = (const float*)d_in[8];
    const float* dep_b  = (const float*)d_in[9];
    const float* rate1  = (const float*)d_in[10];
    const float* rate2  = (const float*)d_in[11];
    float* out = (float*)d_out;

    if (ws_size >= (size_t)131072 * 384 * 2) {
        ushort_t* qkv = (ushort_t*)d_ws;   // 96 MB bf16
        k_qqkv<<<dim3(12288), dim3(256), 0, stream>>>(x, qkv_w, qkv_b, qkv);
        k_attn2<<<dim3(2048), dim3(256), 0, stream>>>(qkv, proj_w, proj_b,
                                                      rpb, rate1, out);
        k_conv2<<<dim3(512), dim3(256), 0, stream>>>(qkv, fc_w, fc_b, dep_w,
                                                     dep_b, rate2, out);
    } else {
        float* wsf = (float*)d_ws;         // 148.6 KB
        k_prep_f<<<dim3(146), dim3(256), 0, stream>>>(qkv_w, qkv_b, fc_w, fc_b, wsf);
        k_attn_f<<<dim3(2048), dim3(256), 0, stream>>>(x, qkv_w, qkv_b, proj_w,
                                                       proj_b, rpb, rate1, out);
        k_conv_f<<<dim3(512), dim3(256), 0, stream>>>(x, wsf, dep_w, dep_b,
                                                      rate2, out);
    }
}

// Round 4
// 634.191 us; speedup vs baseline: 1.9317x; 1.3600x over previous
//
#include <hip/hip_runtime.h>

typedef unsigned short ushort_t;
typedef unsigned int uint_t;
typedef __attribute__((ext_vector_type(8))) short short8;
typedef __attribute__((ext_vector_type(4))) float f32x4;

#define SCALE 0.17677669529663687f

__device__ __forceinline__ float blo(uint_t u) { return __uint_as_float(u << 16); }
__device__ __forceinline__ float bhi(uint_t u) { return __uint_as_float(u & 0xffff0000u); }
__device__ __forceinline__ float u2f(ushort_t u) { return __uint_as_float(((uint_t)u) << 16); }
// fp32 -> bf16 (RNE), finite inputs
__device__ __forceinline__ ushort_t f2u(float f) {
    const uint_t x = __float_as_uint(f);
    return (ushort_t)((x + 0x7fffu + ((x >> 16) & 1u)) >> 16);
}
__device__ __forceinline__ uint_t pack2(float a, float b) {
    return (uint_t)f2u(a) | ((uint_t)f2u(b) << 16);
}

__device__ __forceinline__ float dot8(const float* qa, uint4 u) {
    return qa[0] * blo(u.x) + qa[1] * bhi(u.x) + qa[2] * blo(u.y) + qa[3] * bhi(u.y)
         + qa[4] * blo(u.z) + qa[5] * bhi(u.z) + qa[6] * blo(u.w) + qa[7] * bhi(u.w);
}
__device__ __forceinline__ void pv8(float* a, float e, uint4 u) {
    a[0] += e * blo(u.x); a[1] += e * bhi(u.x); a[2] += e * blo(u.y); a[3] += e * bhi(u.y);
    a[4] += e * blo(u.z); a[5] += e * bhi(u.z); a[6] += e * blo(u.w); a[7] += e * bhi(u.w);
}

// ==================================================================
// MAIN PATH: qkv materialized in ws as bf16 [p][j], p=131072, j=384.
// Requires ws_size >= 96 MB.
// ==================================================================

// ------------------------------------------------------------------
// k_qqkv (MFMA): qkv[p, j] = bf16( sum_c x[b,c,p]*qkv_w[c,j] + qkv_b[j] )
// Block = 128 pixels x all 384 j (3 j-tiles of 128), K=128.
// XT = x^T tile [p][c] bf16, WT = w^T tile [j][c] bf16, both with
// 16B-block XOR swizzle (blk ^= row&7) -> rows 256B, 16B-aligned,
// ~2-way max bank conflicts on ds_read_b128 / ds_write_b128.
// D = mfma(A=WT row=j, B=XT col=p): 16x16x32 bf16, acc 4x4 per wave.
// D staged back through WT region for coalesced 16B global writes.
// ------------------------------------------------------------------
__global__ __launch_bounds__(256) void k_qqkv(
    const float* __restrict__ x, const float* __restrict__ w,
    const float* __restrict__ wb, ushort_t* __restrict__ qkv)
{
    __shared__ ushort_t XT[128 * 128];  // [p][c] swizzled
    __shared__ ushort_t WT[128 * 128];  // [j][c] swizzled; reused as D [p][j]
    const int t = threadIdx.x;
    const int p0 = blockIdx.x * 128;
    const int b = p0 >> 14;             // HW = 16384
    const int rem = p0 & 16383;
    const float* xb = x + ((size_t)b << 21) + rem;

    // ---- stage XT: x[c][p] -> bf16 XT[p][c] (coalesced reads along p)
#pragma unroll
    for (int it = 0; it < 8; ++it) {
        const int slot = it * 256 + t;
        const int p = slot & 127, cb = slot >> 7;   // cb = 16B block along c
        uint4 u;
        {
            const float a0 = xb[(size_t)(cb * 8 + 0) * 16384 + p];
            const float a1 = xb[(size_t)(cb * 8 + 1) * 16384 + p];
            const float a2 = xb[(size_t)(cb * 8 + 2) * 16384 + p];
            const float a3 = xb[(size_t)(cb * 8 + 3) * 16384 + p];
            const float a4 = xb[(size_t)(cb * 8 + 4) * 16384 + p];
            const float a5 = xb[(size_t)(cb * 8 + 5) * 16384 + p];
            const float a6 = xb[(size_t)(cb * 8 + 6) * 16384 + p];
            const float a7 = xb[(size_t)(cb * 8 + 7) * 16384 + p];
            u.x = pack2(a0, a1); u.y = pack2(a2, a3);
            u.z = pack2(a4, a5); u.w = pack2(a6, a7);
        }
        *(uint4*)&XT[p * 128 + ((cb ^ (p & 7)) << 3)] = u;
    }

    const int l = t & 63, wv = t >> 6;
    const int wj = (wv >> 1) * 64, wp = (wv & 1) * 64;
    const int lr = l & 15, lg = l >> 4;

    for (int jt = 0; jt < 3; ++jt) {
        const int j0 = jt * 128;
        __syncthreads();   // XT ready (jt=0) / prior D drained (jt>0)

        // ---- stage WT: w[c][j0+j] -> bf16 WT[j][c] (coalesced along j; L2-hot)
#pragma unroll
        for (int it = 0; it < 8; ++it) {
            const int slot = it * 256 + t;
            const int j = slot & 127, cb = slot >> 7;
            uint4 u;
            {
                const float a0 = w[(size_t)(cb * 8 + 0) * 384 + j0 + j];
                const float a1 = w[(size_t)(cb * 8 + 1) * 384 + j0 + j];
                const float a2 = w[(size_t)(cb * 8 + 2) * 384 + j0 + j];
                const float a3 = w[(size_t)(cb * 8 + 3) * 384 + j0 + j];
                const float a4 = w[(size_t)(cb * 8 + 4) * 384 + j0 + j];
                const float a5 = w[(size_t)(cb * 8 + 5) * 384 + j0 + j];
                const float a6 = w[(size_t)(cb * 8 + 6) * 384 + j0 + j];
                const float a7 = w[(size_t)(cb * 8 + 7) * 384 + j0 + j];
                u.x = pack2(a0, a1); u.y = pack2(a2, a3);
                u.z = pack2(a4, a5); u.w = pack2(a6, a7);
            }
            *(uint4*)&WT[j * 128 + ((cb ^ (j & 7)) << 3)] = u;
        }
        __syncthreads();

        f32x4 acc[4][4];
#pragma unroll
        for (int i = 0; i < 4; ++i)
#pragma unroll
            for (int j = 0; j < 4; ++j) acc[i][j] = (f32x4){0.f, 0.f, 0.f, 0.f};

#pragma unroll
        for (int ks = 0; ks < 4; ++ks) {
            const int kb = ks * 4 + lg;
            short8 af[4], bf[4];
#pragma unroll
            for (int i = 0; i < 4; ++i) {
                const int jr = wj + i * 16 + lr;
                af[i] = *(const short8*)&WT[jr * 128 + ((kb ^ (jr & 7)) << 3)];
                const int pr = wp + i * 16 + lr;
                bf[i] = *(const short8*)&XT[pr * 128 + ((kb ^ (pr & 7)) << 3)];
            }
#pragma unroll
            for (int ji = 0; ji < 4; ++ji)
#pragma unroll
                for (int pi = 0; pi < 4; ++pi)
                    acc[ji][pi] = __builtin_amdgcn_mfma_f32_16x16x32_bf16(
                        af[ji], bf[pi], acc[ji][pi], 0, 0, 0);
        }
        __syncthreads();   // all WT reads done before D overwrite

        // ---- D write: lane holds 4 consecutive j at fixed p per acc tile
#pragma unroll
        for (int ji = 0; ji < 4; ++ji) {
            const int jq = wj + ji * 16 + 4 * lg;            // local j quad base
            const float4 bias = *(const float4*)&wb[j0 + jq];
#pragma unroll
            for (int pi = 0; pi < 4; ++pi) {
                const int p = wp + pi * 16 + lr;
                uint2 o;
                o.x = pack2(acc[ji][pi][0] + bias.x, acc[ji][pi][1] + bias.y);
                o.y = pack2(acc[ji][pi][2] + bias.z, acc[ji][pi][3] + bias.w);
                *(uint2*)&WT[p * 128 + (((jq >> 3) ^ (p & 7)) << 3) + (jq & 7)] = o;
            }
        }
        __syncthreads();

        // ---- copy D -> qkv, coalesced 16B writes (lanes sweep j)
#pragma unroll
        for (int it = 0; it < 8; ++it) {
            const int slot = it * 256 + t;
            const int seg = slot & 15, p = slot >> 4;
            const uint4 v = *(const uint4*)&WT[p * 128 + ((seg ^ (p & 7)) << 3)];
            *(uint4*)&qkv[(size_t)(p0 + p) * 384 + j0 + seg * 8] = v;
        }
    }
}

// ------------------------------------------------------------------
// k_attn2: per 8x8 window. k/v staged from qkv into LDS (bf16,
// 16B-aligned stride-68-uint rows), q from qkv into regs; FUSED
// online-softmax attention (no score array); rpb staged in LDS;
// proj; OVERWRITE out = rate1 * xa (fp32).
// Thread (h = t>>6, n = t&63).
// ------------------------------------------------------------------
__global__ __launch_bounds__(256, 4) void k_attn2(
    const ushort_t* __restrict__ qkv, const float* __restrict__ pw,
    const float* __restrict__ pb, const float* __restrict__ rpb,
    const float* __restrict__ r1, float* __restrict__ out)
{
    // [0, 8704) uints: k rows (64 x 68) then v rows (64 x 68), bf16 pairs.
    // overlapped later by xa (64 x 130 floats = 8320 < 8704).
    // [8704, 9604) floats: rpb table (225 x 4).
    __shared__ float arena[9604];
    uint_t* kv32 = (uint_t*)arena;
    float* rpbl = arena + 8704;
    const int t = threadIdx.x;
    const int b = blockIdx.x >> 8, wy = (blockIdx.x >> 4) & 15, wx = blockIdx.x & 15;
    const int prow0 = (b << 14) + (wy * 8) * 128 + wx * 8;
    const uint_t* qkvu = (const uint_t*)qkv;

    // stage k (j 128..255) and v (j 256..383): per m, 64 uints each
    for (int i = t; i < 4096; i += 256) {
        const int m = i >> 6, u = i & 63;
        const size_t pr = (size_t)(prow0 + (m >> 3) * 128 + (m & 7)) * 192;
        kv32[m * 68 + u]        = qkvu[pr + 64 + u];
        kv32[4352 + m * 68 + u] = qkvu[pr + 128 + u];
    }
    for (int i = t; i < 900; i += 256) rpbl[i] = rpb[i];

    const int h = t >> 6, n = t & 63;
    const size_t pq = (size_t)(prow0 + (n >> 3) * 128 + (n & 7)) * 192;
    float qa[32];
    const uint_t* qrow = qkvu + pq + h * 16;
#pragma unroll
    for (int j = 0; j < 16; ++j) {
        const uint_t u = qrow[j];
        qa[2 * j]     = blo(u) * SCALE;
        qa[2 * j + 1] = bhi(u) * SCALE;
    }
    __syncthreads();

    const int ry = n >> 3, rx = n & 7;
    const float* rpbl_t = rpbl + h;
    const int rbase = (ry + 7) * 15 + (rx + 7);

    const uint_t* kbase = kv32 + h * 16;
    const uint_t* vbase = kv32 + 4352 + h * 16;

    float mx = -1e30f, l = 0.f;
    float acc[32];
#pragma unroll
    for (int cc = 0; cc < 32; ++cc) acc[cc] = 0.f;

#pragma unroll 4
    for (int m = 0; m < 64; ++m) {
        const uint4* kr = (const uint4*)(kbase + m * 68);
        const uint4 k0 = kr[0], k1 = kr[1], k2 = kr[2], k3 = kr[3];
        float s = (dot8(qa, k0) + dot8(qa + 8, k1))
                + (dot8(qa + 16, k2) + dot8(qa + 24, k3));
        s += rpbl_t[4 * (rbase - (m >> 3) * 15 - (m & 7))];
        if (s > mx) {
            const float sc = __expf(mx - s);
            mx = s;
            l *= sc;
#pragma unroll
            for (int cc = 0; cc < 32; ++cc) acc[cc] *= sc;
        }
        const float e = __expf(s - mx);
        l += e;
        const uint4* vr = (const uint4*)(vbase + m * 68);
        const uint4 v0 = vr[0], v1 = vr[1], v2 = vr[2], v3 = vr[3];
        pv8(acc, e, v0); pv8(acc + 8, e, v1);
        pv8(acc + 16, e, v2); pv8(acc + 24, e, v3);
    }
    const float inv = 1.f / l;

    __syncthreads();   // all k/v reads done
#pragma unroll
    for (int cc = 0; cc < 32; ++cc) arena[n * 130 + h * 32 + cc] = acc[cc] * inv;
    __syncthreads();

    // proj: out = rate1 * (xa @ proj_w + proj_b)
    const int p = t & 63, jb = t >> 6;
    float aj[32];
#pragma unroll
    for (int jj = 0; jj < 32; ++jj) aj[jj] = pb[jb * 32 + jj];
    const float* xr = arena + p * 130;
    const float* pwb = pw + jb * 32;
    for (int c = 0; c < 128; ++c) {
        const float xv = xr[c];
        const float4* pr = (const float4*)(pwb + c * 128);
#pragma unroll
        for (int j = 0; j < 8; ++j) {
            const float4 w4 = pr[j];
            aj[4 * j + 0] += xv * w4.x; aj[4 * j + 1] += xv * w4.y;
            aj[4 * j + 2] += xv * w4.z; aj[4 * j + 3] += xv * w4.w;
        }
    }
    const float rate1 = r1[0];
    const int oy = wy * 8 + (p >> 3), ox = wx * 8 + (p & 7);
    float* ob = out + ((size_t)b << 21) + (size_t)(oy * 128 + ox);
#pragma unroll
    for (int jj = 0; jj < 32; ++jj)
        ob[(size_t)(jb * 32 + jj) << 14] = rate1 * aj[jj];
}

// ------------------------------------------------------------------
// k_conv2: per 16x16 tile, 8 chunks of 4 d.  f_c[i,d] at each 18x18
// halo pixel from materialized qkv (12 MACs per output), zero outside
// the image; then the 81-tap grouped conv; RMW out += rate2*(conv+db).
// ------------------------------------------------------------------
__global__ __launch_bounds__(256) void k_conv2(
    const ushort_t* __restrict__ qkv, const float* __restrict__ fcw,
    const float* __restrict__ fcb, const float* __restrict__ depw,
    const float* __restrict__ depb, const float* __restrict__ r2,
    float* __restrict__ out)
{
    __shared__ float fcl[11664];    // [(ii*4+dd)*324 + pix]
    __shared__ __align__(16) float dwl[1296];   // [kk81][16 oc-in-chunk]
    __shared__ float fcwl[108];
    __shared__ float fcbl[9];

    const int t = threadIdx.x;
    const int b = blockIdx.x >> 6, tile = blockIdx.x & 63;
    const int ty0 = (tile >> 3) << 4, tx0 = (tile & 7) << 4;
    if (t < 108) fcwl[t] = fcw[t];
    if (t < 9)   fcbl[t] = fcb[t];
    const float rate2 = r2[0];
    const int py = t >> 4, px = t & 15;
    float* ob = out + ((size_t)b << 21) + (size_t)((ty0 + py) * 128 + (tx0 + px));

    // this thread's halo pixels: pix0 = t, pix1 = 256+t (t<68)
    const int row0 = t / 18, col0 = t - row0 * 18;
    const int hy0 = ty0 + row0 - 1, hx0 = tx0 + col0 - 1;
    const int g0 = ((unsigned)hy0 < 128u && (unsigned)hx0 < 128u)
                       ? ((b << 14) + hy0 * 128 + hx0) : -1;
    const int t1 = t + 256, row1 = t1 / 18, col1 = t1 - row1 * 18;
    const int hy1 = ty0 + row1 - 1, hx1 = tx0 + col1 - 1;
    const int g1 = (t < 68 && (unsigned)hy1 < 128u && (unsigned)hx1 < 128u)
                       ? ((b << 14) + hy1 * 128 + hx1) : -1;

    for (int chunk = 0; chunk < 8; ++chunk) {
        __syncthreads();   // fcwl visible (chunk 0) / prior conv reads done
        for (int i = t; i < 1296; i += 256)
            dwl[i] = depw[(chunk * 16 + (i & 15)) * 81 + (i >> 4)];

#pragma unroll
        for (int half = 0; half < 2; ++half) {
            const int g = half ? g1 : g0;
            const int pix = half ? (256 + t) : t;
            if (half && t >= 68) break;
            float fo[9][4];
#pragma unroll
            for (int ii = 0; ii < 9; ++ii) {
                const float bv = (g >= 0) ? fcbl[ii] : 0.f;
                fo[ii][0] = bv; fo[ii][1] = bv; fo[ii][2] = bv; fo[ii][3] = bv;
            }
            if (g >= 0) {
                const uint2* qp = (const uint2*)(qkv + (size_t)g * 384 + chunk * 4);
#pragma unroll
                for (int e = 0; e < 12; ++e) {
                    const uint2 q = qp[e * 8];
                    const float f0 = blo(q.x), f1 = bhi(q.x);
                    const float f2 = blo(q.y), f3 = bhi(q.y);
#pragma unroll
                    for (int ii = 0; ii < 9; ++ii) {
                        const float wv = fcwl[ii * 12 + e];
                        fo[ii][0] += wv * f0; fo[ii][1] += wv * f1;
                        fo[ii][2] += wv * f2; fo[ii][3] += wv * f3;
                    }
                }
            }
#pragma unroll
            for (int ii = 0; ii < 9; ++ii)
#pragma unroll
                for (int dd = 0; dd < 4; ++dd)
                    fcl[(ii * 4 + dd) * 324 + pix] = fo[ii][dd];
        }
        __syncthreads();

        float4 accv[4];
#pragma unroll
        for (int dd = 0; dd < 4; ++dd) accv[dd] = make_float4(0.f, 0.f, 0.f, 0.f);
#pragma unroll
        for (int ii = 0; ii < 9; ++ii) {
#pragma unroll
            for (int kk = 0; kk < 9; ++kk) {
                const int ky = kk / 3, kx = kk - (kk / 3) * 3;
                const int hpix = (py + ky) * 18 + px + kx;
                const float4* dwp = (const float4*)&dwl[(ii * 9 + kk) * 16];
#pragma unroll
                for (int dd = 0; dd < 4; ++dd) {
                    const float f = fcl[(ii * 4 + dd) * 324 + hpix];
                    const float4 d4 = dwp[dd];
                    accv[dd].x += f * d4.x; accv[dd].y += f * d4.y;
                    accv[dd].z += f * d4.z; accv[dd].w += f * d4.w;
                }
            }
        }
#pragma unroll
        for (int dd = 0; dd < 4; ++dd) {
            const float av[4] = {accv[dd].x, accv[dd].y, accv[dd].z, accv[dd].w};
#pragma unroll
            for (int j = 0; j < 4; ++j) {
                const int oc = chunk * 16 + dd * 4 + j;
                ob[(size_t)oc << 14] += rate2 * (av[j] + depb[oc]);
            }
        }
    }
}

// ==================================================================
// FALLBACK PATH (ws too small): round-5 kernels, verbatim.
// ==================================================================
#define WS_W2  0
#define WS_B2  36864
#define WS_TOT 37152

__global__ __launch_bounds__(256) void k_prep_f(
    const float* __restrict__ qkv_w, const float* __restrict__ qkv_b,
    const float* __restrict__ fcw, const float* __restrict__ fcb,
    float* __restrict__ ws)
{
    const int idx = blockIdx.x * 256 + threadIdx.x;
    if (idx < WS_B2) {
        const int c = idx / 288, r = idx - c * 288, i = r >> 5, d = r & 31;
        float s = 0.f;
#pragma unroll
        for (int e = 0; e < 12; ++e)
            s += fcw[i * 12 + e] * qkv_w[c * 384 + e * 32 + d];
        ws[idx] = s;
    } else if (idx < WS_TOT) {
        const int r = idx - WS_B2, i = r >> 5, d = r & 31;
        float s = fcb[i];
#pragma unroll
        for (int e = 0; e < 12; ++e)
            s += fcw[i * 12 + e] * qkv_b[e * 32 + d];
        ws[idx] = s;
    }
}

__global__ __launch_bounds__(256) void k_attn_f(
    const float* __restrict__ x, const float* __restrict__ qw,
    const float* __restrict__ qb, const float* __restrict__ pw,
    const float* __restrict__ pb, const float* __restrict__ rpb,
    const float* __restrict__ r1, float* __restrict__ out)
{
    __shared__ ushort_t xw[8192];
    __shared__ float arena[8450];
    ushort_t* kvb = (ushort_t*)arena;
    const int t = threadIdx.x;
    const int b = blockIdx.x >> 8, wy = (blockIdx.x >> 4) & 15, wx = blockIdx.x & 15;
    const size_t xbase = ((size_t)b << 21) + (size_t)((wy * 8) * 128 + wx * 8);
    for (int i = t; i < 8192; i += 256) {
        const int c = i >> 6, p = i & 63;
        xw[i] = f2u(x[xbase + (size_t)c * 16384 + (p >> 3) * 128 + (p & 7)]);
    }
    __syncthreads();
    const int h = t >> 6, n = t & 63;
    float qa[32], ka[32], va[32];
#pragma unroll
    for (int cc = 0; cc < 32; ++cc) {
        qa[cc] = qb[h * 32 + cc];
        ka[cc] = qb[128 + h * 32 + cc];
        va[cc] = qb[256 + h * 32 + cc];
    }
    const float* wbase = qw + h * 32;
    for (int c = 0; c < 128; ++c) {
        const float xv = u2f(xw[c * 64 + n]);
        const float* wr = wbase + c * 384;
#pragma unroll
        for (int j = 0; j < 8; ++j) {
            const float4 aq = ((const float4*)wr)[j];
            const float4 ak = ((const float4*)(wr + 128))[j];
            const float4 av = ((const float4*)(wr + 256))[j];
            qa[4 * j + 0] += xv * aq.x; qa[4 * j + 1] += xv * aq.y;
            qa[4 * j + 2] += xv * aq.z; qa[4 * j + 3] += xv * aq.w;
            ka[4 * j + 0] += xv * ak.x; ka[4 * j + 1] += xv * ak.y;
            ka[4 * j + 2] += xv * ak.z; ka[4 * j + 3] += xv * ak.w;
            va[4 * j + 0] += xv * av.x; va[4 * j + 1] += xv * av.y;
            va[4 * j + 2] += xv * av.z; va[4 * j + 3] += xv * av.w;
        }
    }
#pragma unroll
    for (int cc = 0; cc < 32; ++cc) qa[cc] *= SCALE;
    uint_t* kv32 = (uint_t*)kvb;
#pragma unroll
    for (int j = 0; j < 16; ++j) {
        kv32[n * 66 + h * 16 + j] = pack2(ka[2 * j], ka[2 * j + 1]);
        kv32[4224 + n * 66 + h * 16 + j] = pack2(va[2 * j], va[2 * j + 1]);
    }
    __syncthreads();
    const int ry = n >> 3, rx = n & 7;
    float sar[64];
    float mx = -1e30f;
#pragma unroll
    for (int m = 0; m < 64; ++m) {
        const uint2* kr = (const uint2*)(kvb + m * 132 + h * 32);
        float s = 0.f;
#pragma unroll
        for (int j = 0; j < 8; ++j) {
            const uint2 u = kr[j];
            s += qa[4 * j + 0] * blo(u.x) + qa[4 * j + 1] * bhi(u.x)
               + qa[4 * j + 2] * blo(u.y) + qa[4 * j + 3] * bhi(u.y);
        }
        s += rpb[((ry - (m >> 3) + 7) * 15 + (rx - (m & 7) + 7)) * 4 + h];
        sar[m] = s;
        mx = fmaxf(mx, s);
    }
    float l = 0.f;
#pragma unroll
    for (int m = 0; m < 64; ++m) { const float e = __expf(sar[m] - mx); sar[m] = e; l += e; }
    const float inv = 1.f / l;
    float acc[32];
#pragma unroll
    for (int cc = 0; cc < 32; ++cc) acc[cc] = 0.f;
#pragma unroll
    for (int m = 0; m < 64; ++m) {
        const float pm = sar[m];
        const uint2* vr = (const uint2*)(kvb + 8448 + m * 132 + h * 32);
#pragma unroll
        for (int j = 0; j < 8; ++j) {
            const uint2 u = vr[j];
            acc[4 * j + 0] += pm * blo(u.x); acc[4 * j + 1] += pm * bhi(u.x);
            acc[4 * j + 2] += pm * blo(u.y); acc[4 * j + 3] += pm * bhi(u.y);
        }
    }
    __syncthreads();
#pragma unroll
    for (int cc = 0; cc < 32; ++cc) arena[n * 130 + h * 32 + cc] = acc[cc] * inv;
    __syncthreads();
    const int p = t & 63, jb = t >> 6;
    float aj[32];
#pragma unroll
    for (int jj = 0; jj < 32; ++jj) aj[jj] = pb[jb * 32 + jj];
    const float* xr = arena + p * 130;
    const float* pwb = pw + jb * 32;
    for (int c = 0; c < 128; ++c) {
        const float xv = xr[c];
        const float4* pr = (const float4*)(pwb + c * 128);
#pragma unroll
        for (int j = 0; j < 8; ++j) {
            const float4 w4 = pr[j];
            aj[4 * j + 0] += xv * w4.x; aj[4 * j + 1] += xv * w4.y;
            aj[4 * j + 2] += xv * w4.z; aj[4 * j + 3] += xv * w4.w;
        }
    }
    const float rate1 = r1[0];
    const int oy = wy * 8 + (p >> 3), ox = wx * 8 + (p & 7);
    float* ob = out + ((size_t)b << 21) + (size_t)(oy * 128 + ox);
#pragma unroll
    for (int jj = 0; jj < 32; ++jj)
        ob[(size_t)(jb * 32 + jj) << 14] = rate1 * aj[jj];
}

__global__ __launch_bounds__(256) void k_conv_f(
    const float* __restrict__ x, const float* __restrict__ ws,
    const float* __restrict__ depw, const float* __restrict__ depb,
    const float* __restrict__ r2, float* __restrict__ out)
{
    __shared__ float arena[12960];
    __shared__ float b2s[36];
    float* w2l = arena;
    ushort_t* xl = (ushort_t*)(arena + 4608);
    float* fcl = arena;
    float* dwl = arena + 11664;
    const int t = threadIdx.x;
    const int b = blockIdx.x >> 6, tile = blockIdx.x & 63;
    const int ty0 = (tile >> 3) << 4, tx0 = (tile & 7) << 4;
    const size_t xbase = ((size_t)b << 21);
    const float rate2 = r2[0];
    const int py = t >> 4, px = t & 15;
    float* ob = out + ((size_t)b << 21) + (size_t)((ty0 + py) * 128 + (tx0 + px));
    const int r0 = t / 18, c0 = t - r0 * 18;
    const bool ok0 = ((unsigned)(ty0 + r0 - 1) < 128u) && ((unsigned)(tx0 + c0 - 1) < 128u);
    const int t1 = 256 + t, r1i = t1 / 18, c1 = t1 - r1i * 18;
    const bool ok1 = (t < 68) && ((unsigned)(ty0 + r1i - 1) < 128u) && ((unsigned)(tx0 + c1 - 1) < 128u);
    for (int chunk = 0; chunk < 8; ++chunk) {
        __syncthreads();
        for (int i = t; i < 4608; i += 256) {
            const int c = i / 36, r = i - c * 36;
            w2l[i] = ws[WS_W2 + c * 288 + (r >> 2) * 32 + chunk * 4 + (r & 3)];
        }
        if (t < 36) b2s[t] = ws[WS_B2 + (t >> 2) * 32 + chunk * 4 + (t & 3)];
        __syncthreads();
        float fca[2][36];
#pragma unroll
        for (int r = 0; r < 36; ++r) { fca[0][r] = b2s[r]; fca[1][r] = b2s[r]; }
        for (int cs = 0; cs < 8; ++cs) {
            if (cs) __syncthreads();
            for (int i = t; i < 5184; i += 256) {
                const int cc = i / 324, pp = i - cc * 324;
                const int row = pp / 18, col = pp - row * 18;
                const int hy = ty0 + row - 1, hx = tx0 + col - 1;
                ushort_t v = 0;
                if ((unsigned)hy < 128u && (unsigned)hx < 128u)
                    v = f2u(x[xbase + (size_t)(cs * 16 + cc) * 16384 + hy * 128 + hx]);
                xl[i] = v;
            }
            __syncthreads();
#pragma unroll 4
            for (int cc = 0; cc < 16; ++cc) {
                const float xv0 = u2f(xl[cc * 324 + t]);
                const float xv1 = (t < 68) ? u2f(xl[cc * 324 + 256 + t]) : 0.f;
                const float* wr = w2l + (cs * 16 + cc) * 36;
#pragma unroll
                for (int r = 0; r < 36; r += 4) {
                    const float4 w4 = *(const float4*)(wr + r);
                    fca[0][r + 0] += xv0 * w4.x; fca[0][r + 1] += xv0 * w4.y;
                    fca[0][r + 2] += xv0 * w4.z; fca[0][r + 3] += xv0 * w4.w;
                    fca[1][r + 0] += xv1 * w4.x; fca[1][r + 1] += xv1 * w4.y;
                    fca[1][r + 2] += xv1 * w4.z; fca[1][r + 3] += xv1 * w4.w;
                }
            }
        }
        __syncthreads();
#pragma unroll
        for (int r = 0; r < 36; ++r) {
            fcl[r * 324 + t] = ok0 ? fca[0][r] : 0.f;
            if (t < 68) fcl[r * 324 + 256 + t] = ok1 ? fca[1][r] : 0.f;
        }
        for (int i = t; i < 1296; i += 256) {
            const int kk = i >> 4, ocl = i & 15;
            dwl[i] = depw[(chunk * 16 + ocl) * 81 + kk];
        }
        __syncthreads();
        float4 accv[4];
#pragma unroll
        for (int dd = 0; dd < 4; ++dd) accv[dd] = make_float4(0.f, 0.f, 0.f, 0.f);
#pragma unroll
        for (int ii = 0; ii < 9; ++ii) {
#pragma unroll
            for (int kk = 0; kk < 9; ++kk) {
                const int ky = kk / 3, kx = kk - (kk / 3) * 3;
                const int hpix = (py + ky) * 18 + px + kx;
                const float4* dwp = (const float4*)&dwl[(ii * 9 + kk) * 16];
#pragma unroll
                for (int dd = 0; dd < 4; ++dd) {
                    const float f = fcl[(ii * 4 + dd) * 324 + hpix];
                    const float4 d4 = dwp[dd];
                    accv[dd].x += f * d4.x; accv[dd].y += f * d4.y;
                    accv[dd].z += f * d4.z; accv[dd].w += f * d4.w;
                }
            }
        }
#pragma unroll
        for (int dd = 0; dd < 4; ++dd) {
            const float av[4] = {accv[dd].x, accv[dd].y, accv[dd].z, accv[dd].w};
#pragma unroll
            for (int j = 0; j < 4; ++j) {
                const int oc = chunk * 16 + dd * 4 + j;
                ob[(size_t)oc << 14] += rate2 * (av[j] + depb[oc]);
            }
        }
    }
}

// ------------------------------------------------------------------
extern "C" void kernel_launch(void* const* d_in, const int* in_sizes, int n_in,
                              void* d_out, int out_size, void* d_ws, size_t ws_size,
                              hipStream_t stream) {
    (void)in_sizes; (void)n_in; (void)out_size;
    const float* x      = (const float*)d_in[0];
    const float* qkv_w  = (const float*)d_in[1];
    const float* qkv_b  = (const float*)d_in[2];
    const float* proj_w = (const float*)d_in[3];
    const float* proj_b = (const float*)d_in[4];
    const float* rpb    = (const float*)d_in[5];
    const float* fc_w   = (const float*)d_in[6];
    const float* fc_b   = (const float*)d_in[7];
    const float* dep_w  = (const float*)d_in[8];
    const float* dep_b  = (const float*)d_in[9];
    const float* rate1  = (const float*)d_in[10];
    const float* rate2  = (const float*)d_in[11];
    float* out = (float*)d_out;

    if (ws_size >= (size_t)131072 * 384 * 2) {
        ushort_t* qkv = (ushort_t*)d_ws;   // 96 MB bf16
        k_qqkv<<<dim3(1024), dim3(256), 0, stream>>>(x, qkv_w, qkv_b, qkv);
        k_attn2<<<dim3(2048), dim3(256), 0, stream>>>(qkv, proj_w, proj_b,
                                                      rpb, rate1, out);
        k_conv2<<<dim3(512), dim3(256), 0, stream>>>(qkv, fc_w, fc_b, dep_w,
                                                     dep_b, rate2, out);
    } else {
        float* wsf = (float*)d_ws;         // 148.6 KB
        k_prep_f<<<dim3(146), dim3(256), 0, stream>>>(qkv_w, qkv_b, fc_w, fc_b, wsf);
        k_attn_f<<<dim3(2048), dim3(256), 0, stream>>>(x, qkv_w, qkv_b, proj_w,
                                                       proj_b, rpb, rate1, out);
        k_conv_f<<<dim3(512), dim3(256), 0, stream>>>(x, wsf, dep_w, dep_b,
                                                      rate2, out);
    }
}

// Round 6
// 496.166 us; speedup vs baseline: 2.4690x; 1.2782x over previous
//
#include <hip/hip_runtime.h>

typedef unsigned short ushort_t;
typedef unsigned int uint_t;
typedef __attribute__((ext_vector_type(8))) short short8;
typedef __attribute__((ext_vector_type(4))) float f32x4;

#define SCALE 0.17677669529663687f

__device__ __forceinline__ float blo(uint_t u) { return __uint_as_float(u << 16); }
__device__ __forceinline__ float bhi(uint_t u) { return __uint_as_float(u & 0xffff0000u); }
__device__ __forceinline__ float u2f(ushort_t u) { return __uint_as_float(((uint_t)u) << 16); }
// fp32 -> bf16 (RNE), finite inputs
__device__ __forceinline__ ushort_t f2u(float f) {
    const uint_t x = __float_as_uint(f);
    return (ushort_t)((x + 0x7fffu + ((x >> 16) & 1u)) >> 16);
}
__device__ __forceinline__ uint_t pack2(float a, float b) {
    return (uint_t)f2u(a) | ((uint_t)f2u(b) << 16);
}

__device__ __forceinline__ float dot8(const float* qa, uint4 u) {
    return qa[0] * blo(u.x) + qa[1] * bhi(u.x) + qa[2] * blo(u.y) + qa[3] * bhi(u.y)
         + qa[4] * blo(u.z) + qa[5] * bhi(u.z) + qa[6] * blo(u.w) + qa[7] * bhi(u.w);
}
__device__ __forceinline__ void pv8(float* a, float e, uint4 u) {
    a[0] += e * blo(u.x); a[1] += e * bhi(u.x); a[2] += e * blo(u.y); a[3] += e * bhi(u.y);
    a[4] += e * blo(u.z); a[5] += e * bhi(u.z); a[6] += e * blo(u.w); a[7] += e * bhi(u.w);
}

// ==================================================================
// MAIN PATH: qkv materialized in ws as bf16 [p][j], p=131072, j=384.
// Requires ws_size >= 96 MB.
// ==================================================================

// ------------------------------------------------------------------
// k_qqkv (MFMA): qkv[p, j] = bf16( sum_c x[b,c,p]*qkv_w[c,j] + qkv_b[j] )
// Block = 128 pixels x all 384 j (3 j-tiles of 128), K=128.
// ------------------------------------------------------------------
__global__ __launch_bounds__(256) void k_qqkv(
    const float* __restrict__ x, const float* __restrict__ w,
    const float* __restrict__ wb, ushort_t* __restrict__ qkv)
{
    __shared__ ushort_t XT[128 * 128];  // [p][c] swizzled
    __shared__ ushort_t WT[128 * 128];  // [j][c] swizzled; reused as D [p][j]
    const int t = threadIdx.x;
    const int p0 = blockIdx.x * 128;
    const int b = p0 >> 14;             // HW = 16384
    const int rem = p0 & 16383;
    const float* xb = x + ((size_t)b << 21) + rem;

    // ---- stage XT: x[c][p] -> bf16 XT[p][c] (coalesced reads along p)
#pragma unroll
    for (int it = 0; it < 8; ++it) {
        const int slot = it * 256 + t;
        const int p = slot & 127, cb = slot >> 7;   // cb = 16B block along c
        uint4 u;
        {
            const float a0 = xb[(size_t)(cb * 8 + 0) * 16384 + p];
            const float a1 = xb[(size_t)(cb * 8 + 1) * 16384 + p];
            const float a2 = xb[(size_t)(cb * 8 + 2) * 16384 + p];
            const float a3 = xb[(size_t)(cb * 8 + 3) * 16384 + p];
            const float a4 = xb[(size_t)(cb * 8 + 4) * 16384 + p];
            const float a5 = xb[(size_t)(cb * 8 + 5) * 16384 + p];
            const float a6 = xb[(size_t)(cb * 8 + 6) * 16384 + p];
            const float a7 = xb[(size_t)(cb * 8 + 7) * 16384 + p];
            u.x = pack2(a0, a1); u.y = pack2(a2, a3);
            u.z = pack2(a4, a5); u.w = pack2(a6, a7);
        }
        *(uint4*)&XT[p * 128 + ((cb ^ (p & 7)) << 3)] = u;
    }

    const int l = t & 63, wv = t >> 6;
    const int wj = (wv >> 1) * 64, wp = (wv & 1) * 64;
    const int lr = l & 15, lg = l >> 4;

    for (int jt = 0; jt < 3; ++jt) {
        const int j0 = jt * 128;
        __syncthreads();   // XT ready (jt=0) / prior D drained (jt>0)

        // ---- stage WT: w[c][j0+j] -> bf16 WT[j][c] (coalesced along j; L2-hot)
#pragma unroll
        for (int it = 0; it < 8; ++it) {
            const int slot = it * 256 + t;
            const int j = slot & 127, cb = slot >> 7;
            uint4 u;
            {
                const float a0 = w[(size_t)(cb * 8 + 0) * 384 + j0 + j];
                const float a1 = w[(size_t)(cb * 8 + 1) * 384 + j0 + j];
                const float a2 = w[(size_t)(cb * 8 + 2) * 384 + j0 + j];
                const float a3 = w[(size_t)(cb * 8 + 3) * 384 + j0 + j];
                const float a4 = w[(size_t)(cb * 8 + 4) * 384 + j0 + j];
                const float a5 = w[(size_t)(cb * 8 + 5) * 384 + j0 + j];
                const float a6 = w[(size_t)(cb * 8 + 6) * 384 + j0 + j];
                const float a7 = w[(size_t)(cb * 8 + 7) * 384 + j0 + j];
                u.x = pack2(a0, a1); u.y = pack2(a2, a3);
                u.z = pack2(a4, a5); u.w = pack2(a6, a7);
            }
            *(uint4*)&WT[j * 128 + ((cb ^ (j & 7)) << 3)] = u;
        }
        __syncthreads();

        f32x4 acc[4][4];
#pragma unroll
        for (int i = 0; i < 4; ++i)
#pragma unroll
            for (int j = 0; j < 4; ++j) acc[i][j] = (f32x4){0.f, 0.f, 0.f, 0.f};

#pragma unroll
        for (int ks = 0; ks < 4; ++ks) {
            const int kb = ks * 4 + lg;
            short8 af[4], bf[4];
#pragma unroll
            for (int i = 0; i < 4; ++i) {
                const int jr = wj + i * 16 + lr;
                af[i] = *(const short8*)&WT[jr * 128 + ((kb ^ (jr & 7)) << 3)];
                const int pr = wp + i * 16 + lr;
                bf[i] = *(const short8*)&XT[pr * 128 + ((kb ^ (pr & 7)) << 3)];
            }
#pragma unroll
            for (int ji = 0; ji < 4; ++ji)
#pragma unroll
                for (int pi = 0; pi < 4; ++pi)
                    acc[ji][pi] = __builtin_amdgcn_mfma_f32_16x16x32_bf16(
                        af[ji], bf[pi], acc[ji][pi], 0, 0, 0);
        }
        __syncthreads();   // all WT reads done before D overwrite

        // ---- D write: lane holds 4 consecutive j at fixed p per acc tile
#pragma unroll
        for (int ji = 0; ji < 4; ++ji) {
            const int jq = wj + ji * 16 + 4 * lg;            // local j quad base
            const float4 bias = *(const float4*)&wb[j0 + jq];
#pragma unroll
            for (int pi = 0; pi < 4; ++pi) {
                const int p = wp + pi * 16 + lr;
                uint2 o;
                o.x = pack2(acc[ji][pi][0] + bias.x, acc[ji][pi][1] + bias.y);
                o.y = pack2(acc[ji][pi][2] + bias.z, acc[ji][pi][3] + bias.w);
                *(uint2*)&WT[p * 128 + (((jq >> 3) ^ (p & 7)) << 3) + (jq & 7)] = o;
            }
        }
        __syncthreads();

        // ---- copy D -> qkv, coalesced 16B writes (lanes sweep j)
#pragma unroll
        for (int it = 0; it < 8; ++it) {
            const int slot = it * 256 + t;
            const int seg = slot & 15, p = slot >> 4;
            const uint4 v = *(const uint4*)&WT[p * 128 + ((seg ^ (p & 7)) << 3)];
            *(uint4*)&qkv[(size_t)(p0 + p) * 384 + j0 + seg * 8] = v;
        }
    }
}

// ------------------------------------------------------------------
// k_attn3: per 8x8 window. ATTENTION ONLY (QK + online softmax + PV).
// Writes raw xa (fp32, channel-major [b][c][p]) into out; proj is a
// separate MFMA kernel (k_proj) that reads/writes out in place.
// Thread (h = t>>6, n = t&63).
// ------------------------------------------------------------------
__global__ __launch_bounds__(256, 4) void k_attn3(
    const ushort_t* __restrict__ qkv, const float* __restrict__ rpb,
    float* __restrict__ out)
{
    // [0, 8704) uints: k rows (64 x 68) then v rows (64 x 68), bf16 pairs.
    // [8704, 9604) floats: rpb table (225 x 4).
    __shared__ float arena[9604];
    uint_t* kv32 = (uint_t*)arena;
    float* rpbl = arena + 8704;
    const int t = threadIdx.x;
    const int b = blockIdx.x >> 8, wy = (blockIdx.x >> 4) & 15, wx = blockIdx.x & 15;
    const int prow0 = (b << 14) + (wy * 8) * 128 + wx * 8;
    const uint_t* qkvu = (const uint_t*)qkv;

    // stage k (j 128..255) and v (j 256..383): per m, 64 uints each
    for (int i = t; i < 4096; i += 256) {
        const int m = i >> 6, u = i & 63;
        const size_t pr = (size_t)(prow0 + (m >> 3) * 128 + (m & 7)) * 192;
        kv32[m * 68 + u]        = qkvu[pr + 64 + u];
        kv32[4352 + m * 68 + u] = qkvu[pr + 128 + u];
    }
    for (int i = t; i < 900; i += 256) rpbl[i] = rpb[i];

    const int h = t >> 6, n = t & 63;
    const size_t pq = (size_t)(prow0 + (n >> 3) * 128 + (n & 7)) * 192;
    float qa[32];
    const uint_t* qrow = qkvu + pq + h * 16;
#pragma unroll
    for (int j = 0; j < 16; ++j) {
        const uint_t u = qrow[j];
        qa[2 * j]     = blo(u) * SCALE;
        qa[2 * j + 1] = bhi(u) * SCALE;
    }
    __syncthreads();

    const int ry = n >> 3, rx = n & 7;
    const float* rpbl_t = rpbl + h;
    const int rbase = (ry + 7) * 15 + (rx + 7);

    const uint_t* kbase = kv32 + h * 16;
    const uint_t* vbase = kv32 + 4352 + h * 16;

    float mx = -1e30f, l = 0.f;
    float acc[32];
#pragma unroll
    for (int cc = 0; cc < 32; ++cc) acc[cc] = 0.f;

#pragma unroll 4
    for (int m = 0; m < 64; ++m) {
        const uint4* kr = (const uint4*)(kbase + m * 68);
        const uint4 k0 = kr[0], k1 = kr[1], k2 = kr[2], k3 = kr[3];
        float s = (dot8(qa, k0) + dot8(qa + 8, k1))
                + (dot8(qa + 16, k2) + dot8(qa + 24, k3));
        s += rpbl_t[4 * (rbase - (m >> 3) * 15 - (m & 7))];
        if (s > mx) {
            const float sc = __expf(mx - s);
            mx = s;
            l *= sc;
#pragma unroll
            for (int cc = 0; cc < 32; ++cc) acc[cc] *= sc;
        }
        const float e = __expf(s - mx);
        l += e;
        const uint4* vr = (const uint4*)(vbase + m * 68);
        const uint4 v0 = vr[0], v1 = vr[1], v2 = vr[2], v3 = vr[3];
        pv8(acc, e, v0); pv8(acc + 8, e, v1);
        pv8(acc + 16, e, v2); pv8(acc + 24, e, v3);
    }
    const float inv = 1.f / l;

    // write raw xa, channel-major: out[b][h*32+cc][oy*128+ox]
    const int oy = wy * 8 + ry, ox = wx * 8 + rx;
    float* ob = out + ((size_t)b << 21) + (size_t)(oy * 128 + ox);
#pragma unroll
    for (int cc = 0; cc < 32; ++cc)
        ob[(size_t)(h * 32 + cc) << 14] = acc[cc] * inv;
}

// ------------------------------------------------------------------
// k_proj (MFMA, in-place on out): out[b][j][p] =
//    rate1 * ( sum_c xa[b][c][p] * pw[c][j] + pb[j] ), xa = current out.
// Per block: 128 pixels, all reads staged to LDS before any store.
// Same tile structure as k_qqkv (verified), j-width 128.
// ------------------------------------------------------------------
__global__ __launch_bounds__(256) void k_proj(
    const float* __restrict__ pw, const float* __restrict__ pb,
    const float* __restrict__ r1, float* __restrict__ out)
{
    __shared__ ushort_t XT[128 * 128];  // xa^T [p][c] swizzled
    __shared__ ushort_t WT[128 * 128];  // pw^T [j][c] swizzled
    const int t = threadIdx.x;
    const int p0 = blockIdx.x * 128;
    const int b = p0 >> 14;
    const int rem = p0 & 16383;
    const float* xb = out + ((size_t)b << 21) + rem;

    // ---- stage XT from out (xa), coalesced along p
#pragma unroll
    for (int it = 0; it < 8; ++it) {
        const int slot = it * 256 + t;
        const int p = slot & 127, cb = slot >> 7;
        uint4 u;
        {
            const float a0 = xb[(size_t)(cb * 8 + 0) * 16384 + p];
            const float a1 = xb[(size_t)(cb * 8 + 1) * 16384 + p];
            const float a2 = xb[(size_t)(cb * 8 + 2) * 16384 + p];
            const float a3 = xb[(size_t)(cb * 8 + 3) * 16384 + p];
            const float a4 = xb[(size_t)(cb * 8 + 4) * 16384 + p];
            const float a5 = xb[(size_t)(cb * 8 + 5) * 16384 + p];
            const float a6 = xb[(size_t)(cb * 8 + 6) * 16384 + p];
            const float a7 = xb[(size_t)(cb * 8 + 7) * 16384 + p];
            u.x = pack2(a0, a1); u.y = pack2(a2, a3);
            u.z = pack2(a4, a5); u.w = pack2(a6, a7);
        }
        *(uint4*)&XT[p * 128 + ((cb ^ (p & 7)) << 3)] = u;
    }
    // ---- stage WT from pw (128x128), coalesced along j
#pragma unroll
    for (int it = 0; it < 8; ++it) {
        const int slot = it * 256 + t;
        const int j = slot & 127, cb = slot >> 7;
        uint4 u;
        {
            const float a0 = pw[(size_t)(cb * 8 + 0) * 128 + j];
            const float a1 = pw[(size_t)(cb * 8 + 1) * 128 + j];
            const float a2 = pw[(size_t)(cb * 8 + 2) * 128 + j];
            const float a3 = pw[(size_t)(cb * 8 + 3) * 128 + j];
            const float a4 = pw[(size_t)(cb * 8 + 4) * 128 + j];
            const float a5 = pw[(size_t)(cb * 8 + 5) * 128 + j];
            const float a6 = pw[(size_t)(cb * 8 + 6) * 128 + j];
            const float a7 = pw[(size_t)(cb * 8 + 7) * 128 + j];
            u.x = pack2(a0, a1); u.y = pack2(a2, a3);
            u.z = pack2(a4, a5); u.w = pack2(a6, a7);
        }
        *(uint4*)&WT[j * 128 + ((cb ^ (j & 7)) << 3)] = u;
    }
    __syncthreads();   // all global reads of this block's pixels complete here

    const int l = t & 63, wv = t >> 6;
    const int wj = (wv >> 1) * 64, wp = (wv & 1) * 64;
    const int lr = l & 15, lg = l >> 4;

    f32x4 acc[4][4];
#pragma unroll
    for (int i = 0; i < 4; ++i)
#pragma unroll
        for (int j = 0; j < 4; ++j) acc[i][j] = (f32x4){0.f, 0.f, 0.f, 0.f};

#pragma unroll
    for (int ks = 0; ks < 4; ++ks) {
        const int kb = ks * 4 + lg;
        short8 af[4], bf[4];
#pragma unroll
        for (int i = 0; i < 4; ++i) {
            const int jr = wj + i * 16 + lr;
            af[i] = *(const short8*)&WT[jr * 128 + ((kb ^ (jr & 7)) << 3)];
            const int pr = wp + i * 16 + lr;
            bf[i] = *(const short8*)&XT[pr * 128 + ((kb ^ (pr & 7)) << 3)];
        }
#pragma unroll
        for (int ji = 0; ji < 4; ++ji)
#pragma unroll
            for (int pi = 0; pi < 4; ++pi)
                acc[ji][pi] = __builtin_amdgcn_mfma_f32_16x16x32_bf16(
                    af[ji], bf[pi], acc[ji][pi], 0, 0, 0);
    }

    const float rate1 = r1[0];
    float* obase = out + ((size_t)b << 21) + rem;
    // lane holds j = jq..jq+3 at pixel p; stores are 16-lane p-contiguous
#pragma unroll
    for (int ji = 0; ji < 4; ++ji) {
        const int jq = wj + ji * 16 + 4 * lg;
        const float4 bias = *(const float4*)&pb[jq];
#pragma unroll
        for (int pi = 0; pi < 4; ++pi) {
            const int p = wp + pi * 16 + lr;
            float* op = obase + (size_t)jq * 16384 + p;
            op[0]     = rate1 * (acc[ji][pi][0] + bias.x);
            op[16384] = rate1 * (acc[ji][pi][1] + bias.y);
            op[32768] = rate1 * (acc[ji][pi][2] + bias.z);
            op[49152] = rate1 * (acc[ji][pi][3] + bias.w);
        }
    }
}

// ------------------------------------------------------------------
// k_conv2: per 16x16 tile, 8 chunks of 4 d.  f_c[i,d] at each 18x18
// halo pixel from materialized qkv (12 MACs per output), zero outside
// the image; then the 81-tap grouped conv; RMW out += rate2*(conv+db).
// ------------------------------------------------------------------
__global__ __launch_bounds__(256) void k_conv2(
    const ushort_t* __restrict__ qkv, const float* __restrict__ fcw,
    const float* __restrict__ fcb, const float* __restrict__ depw,
    const float* __restrict__ depb, const float* __restrict__ r2,
    float* __restrict__ out)
{
    __shared__ float fcl[11664];    // [(ii*4+dd)*324 + pix]
    __shared__ __align__(16) float dwl[1296];   // [kk81][16 oc-in-chunk]
    __shared__ float fcwl[108];
    __shared__ float fcbl[9];

    const int t = threadIdx.x;
    const int b = blockIdx.x >> 6, tile = blockIdx.x & 63;
    const int ty0 = (tile >> 3) << 4, tx0 = (tile & 7) << 4;
    if (t < 108) fcwl[t] = fcw[t];
    if (t < 9)   fcbl[t] = fcb[t];
    const float rate2 = r2[0];
    const int py = t >> 4, px = t & 15;
    float* ob = out + ((size_t)b << 21) + (size_t)((ty0 + py) * 128 + (tx0 + px));

    // this thread's halo pixels: pix0 = t, pix1 = 256+t (t<68)
    const int row0 = t / 18, col0 = t - row0 * 18;
    const int hy0 = ty0 + row0 - 1, hx0 = tx0 + col0 - 1;
    const int g0 = ((unsigned)hy0 < 128u && (unsigned)hx0 < 128u)
                       ? ((b << 14) + hy0 * 128 + hx0) : -1;
    const int t1 = t + 256, row1 = t1 / 18, col1 = t1 - row1 * 18;
    const int hy1 = ty0 + row1 - 1, hx1 = tx0 + col1 - 1;
    const int g1 = (t < 68 && (unsigned)hy1 < 128u && (unsigned)hx1 < 128u)
                       ? ((b << 14) + hy1 * 128 + hx1) : -1;

    for (int chunk = 0; chunk < 8; ++chunk) {
        __syncthreads();   // fcwl visible (chunk 0) / prior conv reads done
        for (int i = t; i < 1296; i += 256)
            dwl[i] = depw[(chunk * 16 + (i & 15)) * 81 + (i >> 4)];

#pragma unroll
        for (int half = 0; half < 2; ++half) {
            const int g = half ? g1 : g0;
            const int pix = half ? (256 + t) : t;
            if (half && t >= 68) break;
            float fo[9][4];
#pragma unroll
            for (int ii = 0; ii < 9; ++ii) {
                const float bv = (g >= 0) ? fcbl[ii] : 0.f;
                fo[ii][0] = bv; fo[ii][1] = bv; fo[ii][2] = bv; fo[ii][3] = bv;
            }
            if (g >= 0) {
                const uint2* qp = (const uint2*)(qkv + (size_t)g * 384 + chunk * 4);
#pragma unroll
                for (int e = 0; e < 12; ++e) {
                    const uint2 q = qp[e * 8];
                    const float f0 = blo(q.x), f1 = bhi(q.x);
                    const float f2 = blo(q.y), f3 = bhi(q.y);
#pragma unroll
                    for (int ii = 0; ii < 9; ++ii) {
                        const float wv = fcwl[ii * 12 + e];
                        fo[ii][0] += wv * f0; fo[ii][1] += wv * f1;
                        fo[ii][2] += wv * f2; fo[ii][3] += wv * f3;
                    }
                }
            }
#pragma unroll
            for (int ii = 0; ii < 9; ++ii)
#pragma unroll
                for (int dd = 0; dd < 4; ++dd)
                    fcl[(ii * 4 + dd) * 324 + pix] = fo[ii][dd];
        }
        __syncthreads();

        float4 accv[4];
#pragma unroll
        for (int dd = 0; dd < 4; ++dd) accv[dd] = make_float4(0.f, 0.f, 0.f, 0.f);
#pragma unroll
        for (int ii = 0; ii < 9; ++ii) {
#pragma unroll
            for (int kk = 0; kk < 9; ++kk) {
                const int ky = kk / 3, kx = kk - (kk / 3) * 3;
                const int hpix = (py + ky) * 18 + px + kx;
                const float4* dwp = (const float4*)&dwl[(ii * 9 + kk) * 16];
#pragma unroll
                for (int dd = 0; dd < 4; ++dd) {
                    const float f = fcl[(ii * 4 + dd) * 324 + hpix];
                    const float4 d4 = dwp[dd];
                    accv[dd].x += f * d4.x; accv[dd].y += f * d4.y;
                    accv[dd].z += f * d4.z; accv[dd].w += f * d4.w;
                }
            }
        }
#pragma unroll
        for (int dd = 0; dd < 4; ++dd) {
            const float av[4] = {accv[dd].x, accv[dd].y, accv[dd].z, accv[dd].w};
#pragma unroll
            for (int j = 0; j < 4; ++j) {
                const int oc = chunk * 16 + dd * 4 + j;
                ob[(size_t)oc << 14] += rate2 * (av[j] + depb[oc]);
            }
        }
    }
}

// ==================================================================
// FALLBACK PATH (ws too small): round-5 kernels, verbatim.
// ==================================================================
#define WS_W2  0
#define WS_B2  36864
#define WS_TOT 37152

__global__ __launch_bounds__(256) void k_prep_f(
    const float* __restrict__ qkv_w, const float* __restrict__ qkv_b,
    const float* __restrict__ fcw, const float* __restrict__ fcb,
    float* __restrict__ ws)
{
    const int idx = blockIdx.x * 256 + threadIdx.x;
    if (idx < WS_B2) {
        const int c = idx / 288, r = idx - c * 288, i = r >> 5, d = r & 31;
        float s = 0.f;
#pragma unroll
        for (int e = 0; e < 12; ++e)
            s += fcw[i * 12 + e] * qkv_w[c * 384 + e * 32 + d];
        ws[idx] = s;
    } else if (idx < WS_TOT) {
        const int r = idx - WS_B2, i = r >> 5, d = r & 31;
        float s = fcb[i];
#pragma unroll
        for (int e = 0; e < 12; ++e)
            s += fcw[i * 12 + e] * qkv_b[e * 32 + d];
        ws[idx] = s;
    }
}

__global__ __launch_bounds__(256) void k_attn_f(
    const float* __restrict__ x, const float* __restrict__ qw,
    const float* __restrict__ qb, const float* __restrict__ pw,
    const float* __restrict__ pb, const float* __restrict__ rpb,
    const float* __restrict__ r1, float* __restrict__ out)
{
    __shared__ ushort_t xw[8192];
    __shared__ float arena[8450];
    ushort_t* kvb = (ushort_t*)arena;
    const int t = threadIdx.x;
    const int b = blockIdx.x >> 8, wy = (blockIdx.x >> 4) & 15, wx = blockIdx.x & 15;
    const size_t xbase = ((size_t)b << 21) + (size_t)((wy * 8) * 128 + wx * 8);
    for (int i = t; i < 8192; i += 256) {
        const int c = i >> 6, p = i & 63;
        xw[i] = f2u(x[xbase + (size_t)c * 16384 + (p >> 3) * 128 + (p & 7)]);
    }
    __syncthreads();
    const int h = t >> 6, n = t & 63;
    float qa[32], ka[32], va[32];
#pragma unroll
    for (int cc = 0; cc < 32; ++cc) {
        qa[cc] = qb[h * 32 + cc];
        ka[cc] = qb[128 + h * 32 + cc];
        va[cc] = qb[256 + h * 32 + cc];
    }
    const float* wbase = qw + h * 32;
    for (int c = 0; c < 128; ++c) {
        const float xv = u2f(xw[c * 64 + n]);
        const float* wr = wbase + c * 384;
#pragma unroll
        for (int j = 0; j < 8; ++j) {
            const float4 aq = ((const float4*)wr)[j];
            const float4 ak = ((const float4*)(wr + 128))[j];
            const float4 av = ((const float4*)(wr + 256))[j];
            qa[4 * j + 0] += xv * aq.x; qa[4 * j + 1] += xv * aq.y;
            qa[4 * j + 2] += xv * aq.z; qa[4 * j + 3] += xv * aq.w;
            ka[4 * j + 0] += xv * ak.x; ka[4 * j + 1] += xv * ak.y;
            ka[4 * j + 2] += xv * ak.z; ka[4 * j + 3] += xv * ak.w;
            va[4 * j + 0] += xv * av.x; va[4 * j + 1] += xv * av.y;
            va[4 * j + 2] += xv * av.z; va[4 * j + 3] += xv * av.w;
        }
    }
#pragma unroll
    for (int cc = 0; cc < 32; ++cc) qa[cc] *= SCALE;
    uint_t* kv32 = (uint_t*)kvb;
#pragma unroll
    for (int j = 0; j < 16; ++j) {
        kv32[n * 66 + h * 16 + j] = pack2(ka[2 * j], ka[2 * j + 1]);
        kv32[4224 + n * 66 + h * 16 + j] = pack2(va[2 * j], va[2 * j + 1]);
    }
    __syncthreads();
    const int ry = n >> 3, rx = n & 7;
    float sar[64];
    float mx = -1e30f;
#pragma unroll
    for (int m = 0; m < 64; ++m) {
        const uint2* kr = (const uint2*)(kvb + m * 132 + h * 32);
        float s = 0.f;
#pragma unroll
        for (int j = 0; j < 8; ++j) {
            const uint2 u = kr[j];
            s += qa[4 * j + 0] * blo(u.x) + qa[4 * j + 1] * bhi(u.x)
               + qa[4 * j + 2] * blo(u.y) + qa[4 * j + 3] * bhi(u.y);
        }
        s += rpb[((ry - (m >> 3) + 7) * 15 + (rx - (m & 7) + 7)) * 4 + h];
        sar[m] = s;
        mx = fmaxf(mx, s);
    }
    float l = 0.f;
#pragma unroll
    for (int m = 0; m < 64; ++m) { const float e = __expf(sar[m] - mx); sar[m] = e; l += e; }
    const float inv = 1.f / l;
    float acc[32];
#pragma unroll
    for (int cc = 0; cc < 32; ++cc) acc[cc] = 0.f;
#pragma unroll
    for (int m = 0; m < 64; ++m) {
        const float pm = sar[m];
        const uint2* vr = (const uint2*)(kvb + 8448 + m * 132 + h * 32);
#pragma unroll
        for (int j = 0; j < 8; ++j) {
            const uint2 u = vr[j];
            acc[4 * j + 0] += pm * blo(u.x); acc[4 * j + 1] += pm * bhi(u.x);
            acc[4 * j + 2] += pm * blo(u.y); acc[4 * j + 3] += pm * bhi(u.y);
        }
    }
    __syncthreads();
#pragma unroll
    for (int cc = 0; cc < 32; ++cc) arena[n * 130 + h * 32 + cc] = acc[cc] * inv;
    __syncthreads();
    const int p = t & 63, jb = t >> 6;
    float aj[32];
#pragma unroll
    for (int jj = 0; jj < 32; ++jj) aj[jj] = pb[jb * 32 + jj];
    const float* xr = arena + p * 130;
    const float* pwb = pw + jb * 32;
    for (int c = 0; c < 128; ++c) {
        const float xv = xr[c];
        const float4* pr = (const float4*)(pwb + c * 128);
#pragma unroll
        for (int j = 0; j < 8; ++j) {
            const float4 w4 = pr[j];
            aj[4 * j + 0] += xv * w4.x; aj[4 * j + 1] += xv * w4.y;
            aj[4 * j + 2] += xv * w4.z; aj[4 * j + 3] += xv * w4.w;
        }
    }
    const float rate1 = r1[0];
    const int oy = wy * 8 + (p >> 3), ox = wx * 8 + (p & 7);
    float* ob = out + ((size_t)b << 21) + (size_t)(oy * 128 + ox);
#pragma unroll
    for (int jj = 0; jj < 32; ++jj)
        ob[(size_t)(jb * 32 + jj) << 14] = rate1 * aj[jj];
}

__global__ __launch_bounds__(256) void k_conv_f(
    const float* __restrict__ x, const float* __restrict__ ws,
    const float* __restrict__ depw, const float* __restrict__ depb,
    const float* __restrict__ r2, float* __restrict__ out)
{
    __shared__ float arena[12960];
    __shared__ float b2s[36];
    float* w2l = arena;
    ushort_t* xl = (ushort_t*)(arena + 4608);
    float* fcl = arena;
    float* dwl = arena + 11664;
    const int t = threadIdx.x;
    const int b = blockIdx.x >> 6, tile = blockIdx.x & 63;
    const int ty0 = (tile >> 3) << 4, tx0 = (tile & 7) << 4;
    const size_t xbase = ((size_t)b << 21);
    const float rate2 = r2[0];
    const int py = t >> 4, px = t & 15;
    float* ob = out + ((size_t)b << 21) + (size_t)((ty0 + py) * 128 + (tx0 + px));
    const int r0 = t / 18, c0 = t - r0 * 18;
    const bool ok0 = ((unsigned)(ty0 + r0 - 1) < 128u) && ((unsigned)(tx0 + c0 - 1) < 128u);
    const int t1 = 256 + t, r1i = t1 / 18, c1 = t1 - r1i * 18;
    const bool ok1 = (t < 68) && ((unsigned)(ty0 + r1i - 1) < 128u) && ((unsigned)(tx0 + c1 - 1) < 128u);
    for (int chunk = 0; chunk < 8; ++chunk) {
        __syncthreads();
        for (int i = t; i < 4608; i += 256) {
            const int c = i / 36, r = i - c * 36;
            w2l[i] = ws[WS_W2 + c * 288 + (r >> 2) * 32 + chunk * 4 + (r & 3)];
        }
        if (t < 36) b2s[t] = ws[WS_B2 + (t >> 2) * 32 + chunk * 4 + (t & 3)];
        __syncthreads();
        float fca[2][36];
#pragma unroll
        for (int r = 0; r < 36; ++r) { fca[0][r] = b2s[r]; fca[1][r] = b2s[r]; }
        for (int cs = 0; cs < 8; ++cs) {
            if (cs) __syncthreads();
            for (int i = t; i < 5184; i += 256) {
                const int cc = i / 324, pp = i - cc * 324;
                const int row = pp / 18, col = pp - row * 18;
                const int hy = ty0 + row - 1, hx = tx0 + col - 1;
                ushort_t v = 0;
                if ((unsigned)hy < 128u && (unsigned)hx < 128u)
                    v = f2u(x[xbase + (size_t)(cs * 16 + cc) * 16384 + hy * 128 + hx]);
                xl[i] = v;
            }
            __syncthreads();
#pragma unroll 4
            for (int cc = 0; cc < 16; ++cc) {
                const float xv0 = u2f(xl[cc * 324 + t]);
                const float xv1 = (t < 68) ? u2f(xl[cc * 324 + 256 + t]) : 0.f;
                const float* wr = w2l + (cs * 16 + cc) * 36;
#pragma unroll
                for (int r = 0; r < 36; r += 4) {
                    const float4 w4 = *(const float4*)(wr + r);
                    fca[0][r + 0] += xv0 * w4.x; fca[0][r + 1] += xv0 * w4.y;
                    fca[0][r + 2] += xv0 * w4.z; fca[0][r + 3] += xv0 * w4.w;
                    fca[1][r + 0] += xv1 * w4.x; fca[1][r + 1] += xv1 * w4.y;
                    fca[1][r + 2] += xv1 * w4.z; fca[1][r + 3] += xv1 * w4.w;
                }
            }
        }
        __syncthreads();
#pragma unroll
        for (int r = 0; r < 36; ++r) {
            fcl[r * 324 + t] = ok0 ? fca[0][r] : 0.f;
            if (t < 68) fcl[r * 324 + 256 + t] = ok1 ? fca[1][r] : 0.f;
        }
        for (int i = t; i < 1296; i += 256) {
            const int kk = i >> 4, ocl = i & 15;
            dwl[i] = depw[(chunk * 16 + ocl) * 81 + kk];
        }
        __syncthreads();
        float4 accv[4];
#pragma unroll
        for (int dd = 0; dd < 4; ++dd) accv[dd] = make_float4(0.f, 0.f, 0.f, 0.f);
#pragma unroll
        for (int ii = 0; ii < 9; ++ii) {
#pragma unroll
            for (int kk = 0; kk < 9; ++kk) {
                const int ky = kk / 3, kx = kk - (kk / 3) * 3;
                const int hpix = (py + ky) * 18 + px + kx;
                const float4* dwp = (const float4*)&dwl[(ii * 9 + kk) * 16];
#pragma unroll
                for (int dd = 0; dd < 4; ++dd) {
                    const float f = fcl[(ii * 4 + dd) * 324 + hpix];
                    const float4 d4 = dwp[dd];
                    accv[dd].x += f * d4.x; accv[dd].y += f * d4.y;
                    accv[dd].z += f * d4.z; accv[dd].w += f * d4.w;
                }
            }
        }
#pragma unroll
        for (int dd = 0; dd < 4; ++dd) {
            const float av[4] = {accv[dd].x, accv[dd].y, accv[dd].z, accv[dd].w};
#pragma unroll
            for (int j = 0; j < 4; ++j) {
                const int oc = chunk * 16 + dd * 4 + j;
                ob[(size_t)oc << 14] += rate2 * (av[j] + depb[oc]);
            }
        }
    }
}

// ------------------------------------------------------------------
extern "C" void kernel_launch(void* const* d_in, const int* in_sizes, int n_in,
                              void* d_out, int out_size, void* d_ws, size_t ws_size,
                              hipStream_t stream) {
    (void)in_sizes; (void)n_in; (void)out_size;
    const float* x      = (const float*)d_in[0];
    const float* qkv_w  = (const float*)d_in[1];
    const float* qkv_b  = (const float*)d_in[2];
    const float* proj_w = (const float*)d_in[3];
    const float* proj_b = (const float*)d_in[4];
    const float* rpb    = (const float*)d_in[5];
    const float* fc_w   = (const float*)d_in[6];
    const float* fc_b   = (const float*)d_in[7];
    const float* dep_w  = (const float*)d_in[8];
    const float* dep_b  = (const float*)d_in[9];
    const float* rate1  = (const float*)d_in[10];
    const float* rate2  = (const float*)d_in[11];
    float* out = (float*)d_out;

    if (ws_size >= (size_t)131072 * 384 * 2) {
        ushort_t* qkv = (ushort_t*)d_ws;   // 96 MB bf16
        k_qqkv<<<dim3(1024), dim3(256), 0, stream>>>(x, qkv_w, qkv_b, qkv);
        k_attn3<<<dim3(2048), dim3(256), 0, stream>>>(qkv, rpb, out);
        k_proj<<<dim3(1024), dim3(256), 0, stream>>>(proj_w, proj_b, rate1, out);
        k_conv2<<<dim3(512), dim3(256), 0, stream>>>(qkv, fc_w, fc_b, dep_w,
                                                     dep_b, rate2, out);
    } else {
        float* wsf = (float*)d_ws;         // 148.6 KB
        k_prep_f<<<dim3(146), dim3(256), 0, stream>>>(qkv_w, qkv_b, fc_w, fc_b, wsf);
        k_attn_f<<<dim3(2048), dim3(256), 0, stream>>>(x, qkv_w, qkv_b, proj_w,
                                                       proj_b, rpb, rate1, out);
        k_conv_f<<<dim3(512), dim3(256), 0, stream>>>(x, wsf, dep_w, dep_b,
                                                      rate2, out);
    }
}